// Round 14
// baseline (1012.519 us; speedup 1.0000x reference)
//
#include <hip/hip_runtime.h>
#include <math.h>

#define HID 2048
#define NH 16
#define HD 128
#define INTERD 8192
#define SEQL 2048
#define NBATCH 2
#define NTOK (NBATCH*SEQL)

typedef float f32x4 __attribute__((ext_vector_type(4)));
typedef float f32x16 __attribute__((ext_vector_type(16)));
typedef __bf16 bfx8 __attribute__((ext_vector_type(8)));

__device__ __forceinline__ float bf2f(unsigned short u){
  union { float f; unsigned v; } c; c.v = ((unsigned)u)<<16; return c.f;
}
__device__ __forceinline__ unsigned short f2bf(float f){
  union { float f; unsigned v; } c; c.f = f;
  unsigned r = c.v + 0x7FFFu + ((c.v>>16)&1u);   // RNE
  return (unsigned short)(r>>16);
}

// async global->LDS, 16B/lane; LDS dest = wave-uniform base + lane*16 (proven r3-r13).
__device__ __forceinline__ void gll16(const unsigned short* g, void* l){
  __builtin_amdgcn_global_load_lds(
      (const __attribute__((address_space(1))) unsigned int*)(size_t)(const void*)g,
      (__attribute__((address_space(3))) unsigned int*)(unsigned int)(size_t)l,
      16, 0, 0);
}

__global__ void k_sentinel(float* out){ out[0] = 1.0e9f; }

// ---------------- fp32 -> bf16 conversion (single weight) ----------------
__global__ __launch_bounds__(256) void k_cvt(const float* __restrict__ in,
                                             unsigned short* __restrict__ out, int n4){
  int i = blockIdx.x*256 + threadIdx.x;
  if(i >= n4) return;
  float4 v = reinterpret_cast<const float4*>(in)[i];
  ushort4 o;
  o.x = f2bf(v.x); o.y = f2bf(v.y); o.z = f2bf(v.z); o.w = f2bf(v.w);
  reinterpret_cast<ushort4*>(out)[i] = o;
}

// ---------------- fp32 -> bf16: q,k,v,o weights in one launch (4 x HID*HID) ----------
__global__ __launch_bounds__(256) void k_cvt4(const float* __restrict__ s0,
                                              const float* __restrict__ s1,
                                              const float* __restrict__ s2,
                                              const float* __restrict__ s3,
                                              unsigned short* __restrict__ dst){
  int bid = blockIdx.x;                 // 4 * 4096 blocks
  int seg = bid >> 12, sub = bid & 4095;
  const float* src = seg==0 ? s0 : seg==1 ? s1 : seg==2 ? s2 : s3;
  int i = sub*256 + threadIdx.x;        // float4 units; HID*HID/4 = 4096*256 exactly
  float4 v = reinterpret_cast<const float4*>(src)[i];
  ushort4 o;
  o.x = f2bf(v.x); o.y = f2bf(v.y); o.z = f2bf(v.z); o.w = f2bf(v.w);
  reinterpret_cast<ushort4*>(dst + (size_t)seg*HID*HID)[i] = o;
}

// ---------------- RMSNorm (fp32 in) -> bf16 out ----------------
__global__ __launch_bounds__(256) void k_rmsnorm(const float* __restrict__ x,
                                                 const float* __restrict__ w,
                                                 unsigned short* __restrict__ out){
  int row = blockIdx.x, t = threadIdx.x;
  const float4* xr = reinterpret_cast<const float4*>(x + (size_t)row*HID);
  float4 a = xr[2*t], b = xr[2*t+1];
  float ss = a.x*a.x+a.y*a.y+a.z*a.z+a.w*a.w + b.x*b.x+b.y*b.y+b.z*b.z+b.w*b.w;
  #pragma unroll
  for(int o=1;o<64;o<<=1) ss += __shfl_xor(ss, o);
  __shared__ float red[4];
  if((t&63)==0) red[t>>6] = ss;
  __syncthreads();
  float sc = rsqrtf((red[0]+red[1]+red[2]+red[3])*(1.0f/HID) + 1e-6f);
  const float4* wr = reinterpret_cast<const float4*>(w);
  float4 wa = wr[2*t], wb = wr[2*t+1];
  ushort4 o1, o2;
  o1.x=f2bf(a.x*sc*wa.x); o1.y=f2bf(a.y*sc*wa.y); o1.z=f2bf(a.z*sc*wa.z); o1.w=f2bf(a.w*sc*wa.w);
  o2.x=f2bf(b.x*sc*wb.x); o2.y=f2bf(b.y*sc*wb.y); o2.z=f2bf(b.z*sc*wb.z); o2.w=f2bf(b.w*sc*wb.w);
  ushort4* orow = reinterpret_cast<ushort4*>(out + (size_t)row*HID);
  orow[2*t] = o1; orow[2*t+1] = o2;
}

// ---------------- RoPE tables ----------------
__global__ void k_ropetab(float* __restrict__ cs, float* __restrict__ sn){
  int s = blockIdx.x, j = threadIdx.x;   // 64 threads
  float invf = powf(10000.0f, -(float)j*(1.0f/64.0f));
  float ang = (float)s * invf;
  float c, si;
  sincosf(ang, &si, &c);
  cs[s*64+j] = c; sn[s*64+j] = si;
}

// ---------------- RoPE for Q AND K in one launch (bf16 [tok][ld], Q at +0, K at +HID) --
__global__ __launch_bounds__(256) void k_rope2(unsigned short* qk, int ld,
                                               const float* __restrict__ cs,
                                               const float* __restrict__ sn, float qscale){
  int gid = blockIdx.x*256 + threadIdx.x;
  const int half = NTOK*NH*64;
  int sel = gid >= half;                 // 0 = Q (scaled), 1 = K
  int g = sel ? gid - half : gid;
  int j = g & 63;
  int rh = g >> 6;                       // tok*NH + h
  int tok = rh >> 4, h = rh & 15;
  int s = tok & (SEQL-1);
  unsigned short* base = qk + (size_t)tok*ld + sel*HID + h*HD;
  float scale = sel ? 1.0f : qscale;
  float c = cs[s*64+j], sv = sn[s*64+j];
  float x1 = bf2f(base[j]), x2 = bf2f(base[j+64]);
  base[j]    = f2bf((x1*c - x2*sv)*scale);
  base[j+64] = f2bf((x2*c + x1*sv)*scale);
}

// ---------------- V transpose: VT[b,h,d,s] <- V[tok][ld] (bf16) ----------------
__global__ __launch_bounds__(256) void k_transpose_v(const unsigned short* __restrict__ V,
                                                     int ld,
                                                     unsigned short* __restrict__ VT){
  __shared__ unsigned short T[64*136];
  int bid = blockIdx.x;
  int sb = bid & 31, h = (bid>>5) & 15, b = bid>>9;
  int t = threadIdx.x;
  int s0 = sb<<6;
  int sl = t>>2, dc = (t&3)<<5;
  const unsigned short* src = V + (size_t)(b*SEQL + s0 + sl)*ld + h*HD + dc;
  #pragma unroll
  for(int p=0;p<4;p++){
    bfx8 v = *reinterpret_cast<const bfx8*>(src + p*8);
    *reinterpret_cast<bfx8*>(&T[sl*136 + dc + p*8]) = v;
  }
  __syncthreads();
  int d = t>>1, sh = (t&1)<<5;
  unsigned short* dst = VT + ((size_t)((b*NH + h)*HD + d))*SEQL + s0 + sh;
  #pragma unroll
  for(int p=0;p<4;p++){
    union { bfx8 v; unsigned short u[8]; } o;
    #pragma unroll
    for(int j=0;j<8;j++) o.u[j] = T[(sh + p*8 + j)*136 + d];
    *reinterpret_cast<bfx8*>(dst + p*8) = o.v;
  }
}

// ---- shared pipeline helpers ----
#define BAR   __builtin_amdgcn_s_barrier()
#define LGKM0 { asm volatile("s_waitcnt lgkmcnt(0)":::"memory"); __builtin_amdgcn_sched_barrier(0); }
#define PRIO1 __builtin_amdgcn_s_setprio(1)
#define PRIO0 __builtin_amdgcn_s_setprio(0)

// ==================== GEMM-32 (NEW): 32x32x16 MFMA, 256x128 tile =======================
// Mechanism: 16B ds_read feeds a 32-row fragment -> 2x FLOP per LDS byte vs 16x16x32
// (24 reads : 32 MFMA a 32KFLOP per wave per K64), + 32x32 pipe is ~20% faster (m119).
// Scaffold: r8's proven 2-barrier single-buffer loop, gll16 staging, chunk^(row&7)
// swizzle (8 chunks/row either way -> swizzle identical). 256 thr = 4 waves (2M x 2N),
// wave-tile 128x64 = 4x2 frags of 32x32; acc 4x2 x f32x16. 48KB LDS -> 2 blk/CU.
// Input frag layout (family pattern, 16x16x32-verified analog): lane&31 = row,
// lane>>5 = k-group of 8. C/D (m74/m101): col=lane&31, row=(reg&3)+8*(reg>>2)+4*(lane>>5).
// EPI 0: bf16. EPI 1: fp32 = resid+acc. EPI 2: bf16 = silu(gbuf)*acc.
template<int EPI>
__global__ __launch_bounds__(256) void k_gemm32(const unsigned short* __restrict__ A,
                                                const unsigned short* __restrict__ W,
                                                void* out, const float* __restrict__ resid,
                                                const unsigned short* gbuf,
                                                int M, int N, int K){
  __shared__ unsigned short Alds[256*64];   // 32KB
  __shared__ unsigned short Wlds[128*64];   // 16KB
  int xcd = blockIdx.x & 7, idx = blockIdx.x >> 3;
  int bm0 = ((xcd<<1) + (idx&1)) << 8;      // M=4096 -> 16 m-tiles, 2 per XCD
  int bn0 = (idx>>1) << 7;                  // N/128 n-tiles
  int t = threadIdx.x, w = t>>6, l = t&63;
  int wm = w>>1, wn = w&1;
  int l31 = l & 31, kh = l >> 5;            // 32x32 fragment lane decode
  int lrow = l>>3, lcs = (l&7) ^ lrow;      // staging: pre-swizzled source chunk

  f32x16 acc[4][2];
  #pragma unroll
  for(int i=0;i<4;i++)
    #pragma unroll
    for(int j=0;j<2;j++)
      #pragma unroll
      for(int e=0;e<16;e++) acc[i][j][e] = 0.f;

  for(int k0=0;k0<K;k0+=64){
    __syncthreads();                        // protect previous tile's reads
    // stage A: 256 rows (8 passes), B: 128 rows (4 passes); 12 gll16/thread
    #pragma unroll
    for(int p=0;p<8;p++){
      int br = (w<<3) + (p<<5);             // w*8 + lrow + 32p covers 0..255
      gll16(A + (size_t)(bm0+br+lrow)*K + k0 + lcs*8, (char*)Alds + br*128);
    }
    #pragma unroll
    for(int p=0;p<4;p++){
      int br = (w<<3) + (p<<5);
      gll16(W + (size_t)(bn0+br+lrow)*K + k0 + lcs*8, (char*)Wlds + br*128);
    }
    __syncthreads();
    #pragma unroll
    for(int ks=0;ks<4;ks++){                // 4 ksteps of K=16
      int ch = (ks<<1) + kh;                // 16B chunk 0..7
      bfx8 af[4], bf[2];
      #pragma unroll
      for(int fm=0;fm<4;fm++){
        int row = wm*128 + fm*32 + l31;
        af[fm] = *reinterpret_cast<const bfx8*>((const char*)Alds
                   + row*128 + ((ch ^ (row&7))<<4));
      }
      #pragma unroll
      for(int fn=0;fn<2;fn++){
        int row = wn*64 + fn*32 + l31;
        bf[fn] = *reinterpret_cast<const bfx8*>((const char*)Wlds
                   + row*128 + ((ch ^ (row&7))<<4));
      }
      #pragma unroll
      for(int fm=0;fm<4;fm++)
        #pragma unroll
        for(int fn=0;fn<2;fn++)
          acc[fm][fn] = __builtin_amdgcn_mfma_f32_32x32x16_bf16(af[fm], bf[fn], acc[fm][fn], 0,0,0);
    }
  }

  // epilogue: row = bm0 + wm*128 + fm*32 + (reg&3) + 8*(reg>>2) + 4*kh ; col = ... + l31
  #pragma unroll
  for(int fm=0;fm<4;fm++){
    #pragma unroll
    for(int reg=0;reg<16;reg++){
      int row = bm0 + wm*128 + fm*32 + (reg&3) + ((reg>>2)<<3) + (kh<<2);
      #pragma unroll
      for(int fn=0;fn<2;fn++){
        int col = bn0 + wn*64 + fn*32 + l31;
        size_t o = (size_t)row*N + col;
        float v = acc[fm][fn][reg];
        if(EPI==0){
          reinterpret_cast<unsigned short*>(out)[o] = f2bf(v);
        } else if(EPI==1){
          reinterpret_cast<float*>(out)[o] = resid[o] + v;
        } else {
          float g = bf2f(gbuf[o]);
          float sg = g / (1.0f + __expf(-g));
          reinterpret_cast<unsigned short*>(out)[o] = f2bf(sg*v);
        }
      }
    }
  }
}

// ==================== GEMM-D (r13, proven <=188): 128x128 plain double-buffer =========
template<int EPI>
__global__ __launch_bounds__(256) void k_gemmD(const unsigned short* __restrict__ A,
                                               const unsigned short* __restrict__ W,
                                               void* out, const float* __restrict__ resid,
                                               const unsigned short* gbuf,
                                               int M, int N, int K){
  __shared__ unsigned short Alds[2][128*64];
  __shared__ unsigned short Wlds[2][128*64];
  int xcd = blockIdx.x & 7, idx = blockIdx.x >> 3;
  int bm0 = ((xcd<<2) + (idx&3)) << 7;
  int bn0 = (idx>>2) << 7;
  int t = threadIdx.x, w = t>>6, l = t&63, lr = l&15, lg = l>>4;
  int wm = w>>1, wn = w&1;
  int lrow = l>>3, lcs = (l&7) ^ lrow;
  int nt = K >> 6;

  f32x4 z = {0.f,0.f,0.f,0.f};
  f32x4 acc[4][4];
  #pragma unroll
  for(int i=0;i<4;i++){ acc[i][0]=z; acc[i][1]=z; acc[i][2]=z; acc[i][3]=z; }

  #define DSTG(bb, kk) { _Pragma("unroll") for(int p=0;p<4;p++){ \
      int br = (w<<5) + (p<<3); \
      gll16(A + (size_t)(bm0+br+lrow)*K + (kk) + lcs*8, (char*)Alds[bb] + br*128); \
      gll16(W + (size_t)(bn0+br+lrow)*K + (kk) + lcs*8, (char*)Wlds[bb] + br*128); } }

  DSTG(0, 0)
  __syncthreads();

  for(int kt=0; kt<nt; ++kt){
    int cur = kt & 1;
    int kn = (kt+1 < nt) ? ((kt+1)<<6) : 0;
    DSTG(cur^1, kn)
    #pragma unroll
    for(int ks=0;ks<2;ks++){
      bfx8 af[4], bfr[4];
      #pragma unroll
      for(int fm=0;fm<4;fm++){
        int row = wm*64 + fm*16 + lr;
        af[fm] = *reinterpret_cast<const bfx8*>((const char*)Alds[cur]
                   + row*128 + ((((ks<<2)+lg) ^ (row&7))<<4));
      }
      #pragma unroll
      for(int fn=0;fn<4;fn++){
        int row = wn*64 + fn*16 + lr;
        bfr[fn] = *reinterpret_cast<const bfx8*>((const char*)Wlds[cur]
                   + row*128 + ((((ks<<2)+lg) ^ (row&7))<<4));
      }
      #pragma unroll
      for(int fm=0;fm<4;fm++)
        #pragma unroll
        for(int fn=0;fn<4;fn++)
          acc[fm][fn] = __builtin_amdgcn_mfma_f32_16x16x32_bf16(af[fm], bfr[fn], acc[fm][fn], 0,0,0);
    }
    __syncthreads();
  }
  #undef DSTG

  #pragma unroll
  for(int fm=0;fm<4;fm++){
    #pragma unroll
    for(int rr=0;rr<4;rr++){
      int row = bm0 + wm*64 + fm*16 + (lg<<2) + rr;
      #pragma unroll
      for(int fn=0;fn<4;fn++){
        int col = bn0 + wn*64 + fn*16 + lr;
        size_t o = (size_t)row*N + col;
        float v = acc[fm][fn][rr];
        if(EPI==0){
          reinterpret_cast<unsigned short*>(out)[o] = f2bf(v);
        } else if(EPI==1){
          reinterpret_cast<float*>(out)[o] = resid[o] + v;
        } else {
          float g = bf2f(gbuf[o]);
          float sg = g / (1.0f + __expf(-g));
          reinterpret_cast<unsigned short*>(out)[o] = f2bf(sg*v);
        }
      }
    }
  }
}

// ==================== GEMM-N (r10, proven): 256x128 tile, 3-slot — QKV / O / down =====
template<int EPI>
__global__ __launch_bounds__(512, 2) void k_gemmN(const unsigned short* __restrict__ A,
                                                  const unsigned short* __restrict__ W,
                                                  void* out, const float* __restrict__ resid,
                                                  const unsigned short* gbuf,
                                                  int M, int N, int K){
  __shared__ __align__(16) char lds[3*49152];
  int xcd = blockIdx.x & 7, idx = blockIdx.x >> 3;
  int bm0 = ((xcd<<1) + (idx&1)) << 8;
  int bn0 = (idx>>1) << 7;
  int t = threadIdx.x, w = t>>6, l = t&63, lr = l&15, lg = l>>4;
  int wm = w>>1, wn = w&1;
  int lrow = l>>3, lcs = (l&7) ^ lrow;
  int nt = K >> 6;

  f32x4 z = {0.f,0.f,0.f,0.f};
  f32x4 acc[4][4];
  #pragma unroll
  for(int i=0;i<4;i++){ acc[i][0]=z; acc[i][1]=z; acc[i][2]=z; acc[i][3]=z; }

  const unsigned short* sa[4];
  const unsigned short* sb[2];
  #pragma unroll
  for(int p=0;p<4;p++) sa[p] = A + (size_t)(bm0 + p*64 + (w<<3) + lrow)*K + lcs*8;
  #pragma unroll
  for(int p=0;p<2;p++) sb[p] = W + (size_t)(bn0 + p*64 + (w<<3) + lrow)*K + lcs*8;

  #define NSTG_A(Lp, kk) { _Pragma("unroll") for(int p=0;p<4;p++) \
      gll16(sa[p] + (kk), (Lp) + (p*64 + (w<<3))*128); }
  #define NSTG_B(Lp, kk) { _Pragma("unroll") for(int p=0;p<2;p++) \
      gll16(sb[p] + (kk), (Lp) + 32768 + (p*64 + (w<<3))*128); }
  #define NLD(Lc, ks) { \
    _Pragma("unroll") for(int i=0;i<4;i++){ int row = (wm<<6) + i*16 + lr; \
      af[i] = *reinterpret_cast<const bfx8*>((Lc) + row*128 + ((((ks<<2)+lg)^(row&7))<<4)); } \
    _Pragma("unroll") for(int j=0;j<4;j++){ int row = (wn<<6) + j*16 + lr; \
      bq[j] = *reinterpret_cast<const bfx8*>((Lc) + 32768 + row*128 + ((((ks<<2)+lg)^(row&7))<<4)); } }
  #define NMM { _Pragma("unroll") for(int i=0;i<4;i++) \
                _Pragma("unroll") for(int j=0;j<4;j++) \
      acc[i][j] = __builtin_amdgcn_mfma_f32_16x16x32_bf16(af[i], bq[j], acc[i][j], 0,0,0); }

  char* S0 = lds; char* S1 = lds + 49152; char* S2 = lds + 98304;
  NSTG_A(S0, 0) NSTG_B(S0, 0) NSTG_A(S1, 64) NSTG_B(S1, 64)
  asm volatile("s_waitcnt vmcnt(6)":::"memory");
  BAR;

  bfx8 af[4], bq[4];
  for(int kt=0; kt<nt; ++kt){
    int k2 = (kt+2 < nt) ? ((kt+2)<<6) : 0;
    NLD(S0, 0)
    NSTG_A(S2, k2)
    BAR; LGKM0 PRIO1; NMM PRIO0; BAR;
    NLD(S0, 1)
    NSTG_B(S2, k2)
    BAR; LGKM0 PRIO1; NMM PRIO0;
    asm volatile("s_waitcnt vmcnt(6)":::"memory");
    BAR;
    char* tmp = S0; S0 = S1; S1 = S2; S2 = tmp;
  }
  #undef NSTG_A
  #undef NSTG_B
  #undef NLD
  #undef NMM

  #pragma unroll
  for(int fm=0;fm<4;fm++){
    #pragma unroll
    for(int rr=0;rr<4;rr++){
      int row = bm0 + (wm<<6) + fm*16 + (lg<<2) + rr;
      #pragma unroll
      for(int fn=0;fn<4;fn++){
        int col = bn0 + (wn<<6) + fn*16 + lr;
        size_t o = (size_t)row*N + col;
        float v = acc[fm][fn][rr];
        if(EPI==0){
          reinterpret_cast<unsigned short*>(out)[o] = f2bf(v);
        } else if(EPI==1){
          reinterpret_cast<float*>(out)[o] = resid[o] + v;
        } else {
          float g = bf2f(gbuf[o]);
          float sg = g / (1.0f + __expf(-g));
          reinterpret_cast<unsigned short*>(out)[o] = f2bf(sg*v);
        }
      }
    }
  }
}

// ---------------- Flash attention, causal (unchanged from rounds 4-13) ----------------
__global__ __launch_bounds__(256) void k_attn(const unsigned short* __restrict__ Q,
                                              const unsigned short* __restrict__ Kb,
                                              int ldqk,
                                              const unsigned short* __restrict__ VT,
                                              unsigned short* __restrict__ O){
  __shared__ unsigned short Klds[64*128];
  __shared__ unsigned short Vlds[128*64];
  __shared__ unsigned short Plds[4][16*72];

  int bid = blockIdx.x;
  int xcd = bid & 7, idx = bid >> 3;
  int bh = xcd*4 + (idx & 3);
  int qt = 31 - (idx >> 2);
  int h = bh & 15, b = bh >> 4;
  int q0 = qt << 6;
  int t = threadIdx.x, w = t>>6, l = t&63, lr = l&15, lg = l>>4;
  int q0w = q0 + (w<<4);

  bfx8 qf[4];
  const unsigned short* qrow = Q + (size_t)(b*SEQL + q0w + lr)*ldqk + h*HD;
  #pragma unroll
  for(int ds=0;ds<4;ds++) qf[ds] = *reinterpret_cast<const bfx8*>(qrow + ds*32 + lg*8);

  f32x4 z = {0.f,0.f,0.f,0.f};
  f32x4 oacc[8];
  #pragma unroll
  for(int i=0;i<8;i++) oacc[i] = z;
  float m_run = -1e30f, l_run = 0.f;

  int srow = t>>3, sch = t&7;
  int ntile = qt + 1;
  for(int tl=0; tl<ntile; ++tl){
    int k0 = tl << 6;
    __syncthreads();
    #pragma unroll
    for(int pr=0;pr<2;pr++){
      int row = srow + (pr<<5);
      const unsigned short* ks = Kb + (size_t)(b*SEQL + k0 + row)*ldqk + h*HD;
      #pragma unroll
      for(int pc=0;pc<2;pc++){
        int cl = sch + (pc<<3);
        *reinterpret_cast<bfx8*>((char*)Klds + row*256 + ((cl ^ (row&7))<<4)) =
            *reinterpret_cast<const bfx8*>(ks + cl*8);
      }
    }
    #pragma unroll
    for(int pr=0;pr<4;pr++){
      int row = srow + (pr<<5);
      const unsigned short* vs = VT + ((size_t)((b*NH + h)*HD + row))*SEQL + k0;
      *reinterpret_cast<bfx8*>((char*)Vlds + row*128 + ((sch ^ (row&7))<<4)) =
          *reinterpret_cast<const bfx8*>(vs + sch*8);
    }
    __syncthreads();

    f32x4 sAcc[4];
    sAcc[0]=z; sAcc[1]=z; sAcc[2]=z; sAcc[3]=z;
    #pragma unroll
    for(int ds=0;ds<4;ds++){
      int cha = (ds<<2) + lg;
      #pragma unroll
      for(int kg=0;kg<4;kg++){
        int row = (kg<<4) + lr;
        bfx8 ka = *reinterpret_cast<const bfx8*>((char*)Klds + row*256 + ((cha ^ (row&7))<<4));
        sAcc[kg] = __builtin_amdgcn_mfma_f32_16x16x32_bf16(ka, qf[ds], sAcc[kg], 0,0,0);
      }
    }
    int qg = q0w + lr;
    float p[16];
    float mx = -1e30f;
    #pragma unroll
    for(int kg=0;kg<4;kg++){
      #pragma unroll
      for(int r=0;r<4;r++){
        int kk = k0 + (kg<<4) + (lg<<2) + r;
        float v = (kk <= qg) ? sAcc[kg][r] : -1e30f;
        p[kg*4+r] = v; mx = fmaxf(mx, v);
      }
    }
    mx = fmaxf(mx, __shfl_xor(mx,16));
    mx = fmaxf(mx, __shfl_xor(mx,32));
    float m_new = fmaxf(m_run, mx);
    float fac = __expf(m_run - m_new);
    float ts = 0.f;
    #pragma unroll
    for(int i=0;i<16;i++){ p[i] = __expf(p[i]-m_new); ts += p[i]; }
    ts += __shfl_xor(ts,16); ts += __shfl_xor(ts,32);
    l_run = l_run*fac + ts;
    m_run = m_new;
    char* pb = (char*)&Plds[w][0] + lr*144 + lg*8;
    #pragma unroll
    for(int kg=0;kg<4;kg++){
      unsigned pa = (unsigned)f2bf(p[kg*4+0]) | ((unsigned)f2bf(p[kg*4+1])<<16);
      unsigned pc = (unsigned)f2bf(p[kg*4+2]) | ((unsigned)f2bf(p[kg*4+3])<<16);
      *reinterpret_cast<uint2*>(pb + kg*32) = make_uint2(pa, pc);
    }
    float facr[4];
    #pragma unroll
    for(int r=0;r<4;r++) facr[r] = __shfl(fac, (lg<<2)+r);
    #pragma unroll
    for(int db=0;db<8;db++){
      f32x4 o = oacc[db];
      o[0]*=facr[0]; o[1]*=facr[1]; o[2]*=facr[2]; o[3]*=facr[3];
      oacc[db] = o;
    }
    __syncthreads();
    #pragma unroll
    for(int kh=0;kh<2;kh++){
      bfx8 pf = *reinterpret_cast<const bfx8*>((char*)&Plds[w][0] + lr*144 + kh*64 + lg*16);
      #pragma unroll
      for(int db=0;db<8;db++){
        int row = (db<<4) + lr;
        int lc = (kh<<2) + lg;
        bfx8 vf = *reinterpret_cast<const bfx8*>((char*)Vlds + row*128 + ((lc ^ (row&7))<<4));
        oacc[db] = __builtin_amdgcn_mfma_f32_16x16x32_bf16(pf, vf, oacc[db], 0,0,0);
      }
    }
  }
  float lsr[4];
  #pragma unroll
  for(int r=0;r<4;r++) lsr[r] = 1.0f / __shfl(l_run, (lg<<2)+r);
  #pragma unroll
  for(int db=0;db<8;db++){
    #pragma unroll
    for(int r=0;r<4;r++){
      int row = q0w + (lg<<2) + r;
      O[((size_t)((b*SEQL + row)*NH) + h)*HD + (db<<4) + lr] = f2bf(oacc[db][r]*lsr[r]);
    }
  }
}

// ---------------- host launcher (workspace plan = r10/r13, 145MB) ----------------
extern "C" void kernel_launch(void* const* d_in, const int* in_sizes, int n_in,
                              void* d_out, int out_size, void* d_ws, size_t ws_size,
                              hipStream_t stream){
  const float* x   = (const float*)d_in[0];
  const float* anw = (const float*)d_in[1];
  const float* qw  = (const float*)d_in[2];
  const float* kw  = (const float*)d_in[3];
  const float* vw  = (const float*)d_in[4];
  const float* ow  = (const float*)d_in[5];
  const float* fnw = (const float*)d_in[6];
  const float* gw  = (const float*)d_in[7];
  const float* uw  = (const float*)d_in[8];
  const float* dw  = (const float*)d_in[9];
  float* out = (float*)d_out;

  char* ws = (char*)d_ws;
  size_t off = 0;
  auto alloc = [&](size_t bytes)->char*{ char* p = ws + off; off += (bytes + 255) & ~(size_t)255; return p; };
  unsigned short* Wbuf = (unsigned short*)alloc((size_t)INTERD*HID*2);     // 32 MB
  unsigned short* hb   = (unsigned short*)alloc((size_t)NTOK*HID*2);       // 16 MB
  unsigned short* qkvb = (unsigned short*)alloc((size_t)NTOK*3*HID*2);     // 48 MB
  unsigned short* aob  = (unsigned short*)alloc((size_t)NTOK*HID*2);       // 16 MB
  float*          x1   = (float*)alloc((size_t)NTOK*HID*4);                // 32 MB
  float*          cosb = (float*)alloc((size_t)SEQL*64*4);
  float*          sinb = (float*)alloc((size_t)SEQL*64*4);
  unsigned short* gb   = qkvb;                // 64 MB overlay (qkvb+aob), dead after O-proj
  unsigned short* VT   = (unsigned short*)x1; // 16 MB overlay: x1 written only after attn
  if(ws_size < off){ k_sentinel<<<1,1,0,stream>>>(out); return; }

  k_ropetab<<<SEQL, 64, 0, stream>>>(cosb, sinb);

  // ---- attention sublayer ----
  k_rmsnorm<<<NTOK, 256, 0, stream>>>(x, anw, hb);
  k_cvt4<<<4*(HID*HID/1024), 256, 0, stream>>>(qw, kw, vw, ow, Wbuf);   // q|k|v|o -> Wbuf
  k_gemmN<0><<<16*(3*HID/128), 512, 0, stream>>>(hb, Wbuf, qkvb, nullptr, nullptr, NTOK, 3*HID, HID);  // 768
  k_rope2<<<2*(NTOK*NH*64)/256, 256, 0, stream>>>(qkvb, 3*HID, cosb, sinb, 0.08838834764831845f);
  k_transpose_v<<<NBATCH*NH*(SEQL/64), 256, 0, stream>>>(qkvb + 2*HID, 3*HID, VT);
  k_attn<<<(SEQL/64)*NBATCH*NH, 256, 0, stream>>>(qkvb, qkvb + HID, 3*HID, VT, aob);
  k_gemmN<1><<<16*(HID/128), 512, 0, stream>>>(aob, Wbuf + 3*HID*HID, x1, x, nullptr, NTOK, HID, HID); // 256

  // ---- MLP sublayer (A/B: gate on gemmD control ~188, up on NEW gemm32 treatment) ----
  k_rmsnorm<<<NTOK, 256, 0, stream>>>(x1, fnw, hb);
  k_cvt<<<INTERD*HID/1024, 256, 0, stream>>>(gw, Wbuf, INTERD*HID/4);
  k_gemmD<0><<<(NTOK/128)*(INTERD/128), 256, 0, stream>>>(hb, Wbuf, gb, nullptr, nullptr, NTOK, INTERD, HID); // 2048
  k_cvt<<<INTERD*HID/1024, 256, 0, stream>>>(uw, Wbuf, INTERD*HID/4);
  k_gemm32<2><<<(NTOK/256)*(INTERD/128), 256, 0, stream>>>(hb, Wbuf, gb, nullptr, gb, NTOK, INTERD, HID);     // 1024
  k_cvt<<<INTERD*HID/1024, 256, 0, stream>>>(dw, Wbuf, INTERD*HID/4);
  k_gemmN<1><<<16*(HID/128), 512, 0, stream>>>(gb, Wbuf, out, x1, nullptr, NTOK, HID, INTERD);                // 256
}

// Round 15
// 901.787 us; speedup vs baseline: 1.1228x; 1.1228x over previous
//
#include <hip/hip_runtime.h>
#include <math.h>

#define HID 2048
#define NH 16
#define HD 128
#define INTERD 8192
#define SEQL 2048
#define NBATCH 2
#define NTOK (NBATCH*SEQL)

typedef float f32x4 __attribute__((ext_vector_type(4)));
typedef __bf16 bfx8 __attribute__((ext_vector_type(8)));

__device__ __forceinline__ float bf2f(unsigned short u){
  union { float f; unsigned v; } c; c.v = ((unsigned)u)<<16; return c.f;
}
__device__ __forceinline__ unsigned short f2bf(float f){
  union { float f; unsigned v; } c; c.f = f;
  unsigned r = c.v + 0x7FFFu + ((c.v>>16)&1u);   // RNE
  return (unsigned short)(r>>16);
}

// async global->LDS, 16B/lane; LDS dest = wave-uniform base + lane*16 (proven r3-r14).
__device__ __forceinline__ void gll16(const unsigned short* g, void* l){
  __builtin_amdgcn_global_load_lds(
      (const __attribute__((address_space(1))) unsigned int*)(size_t)(const void*)g,
      (__attribute__((address_space(3))) unsigned int*)(unsigned int)(size_t)l,
      16, 0, 0);
}

__global__ void k_sentinel(float* out){ out[0] = 1.0e9f; }

// ---------------- fp32 -> bf16 conversion (weights) ----------------
__global__ __launch_bounds__(256) void k_cvt(const float* __restrict__ in,
                                             unsigned short* __restrict__ out, int n4){
  int i = blockIdx.x*256 + threadIdx.x;
  if(i >= n4) return;
  float4 v = reinterpret_cast<const float4*>(in)[i];
  ushort4 o;
  o.x = f2bf(v.x); o.y = f2bf(v.y); o.z = f2bf(v.z); o.w = f2bf(v.w);
  reinterpret_cast<ushort4*>(out)[i] = o;
}

// ---------------- RMSNorm (fp32 in) -> bf16 out ----------------
__global__ __launch_bounds__(256) void k_rmsnorm(const float* __restrict__ x,
                                                 const float* __restrict__ w,
                                                 unsigned short* __restrict__ out){
  int row = blockIdx.x, t = threadIdx.x;
  const float4* xr = reinterpret_cast<const float4*>(x + (size_t)row*HID);
  float4 a = xr[2*t], b = xr[2*t+1];
  float ss = a.x*a.x+a.y*a.y+a.z*a.z+a.w*a.w + b.x*b.x+b.y*b.y+b.z*b.z+b.w*b.w;
  #pragma unroll
  for(int o=1;o<64;o<<=1) ss += __shfl_xor(ss, o);
  __shared__ float red[4];
  if((t&63)==0) red[t>>6] = ss;
  __syncthreads();
  float sc = rsqrtf((red[0]+red[1]+red[2]+red[3])*(1.0f/HID) + 1e-6f);
  const float4* wr = reinterpret_cast<const float4*>(w);
  float4 wa = wr[2*t], wb = wr[2*t+1];
  ushort4 o1, o2;
  o1.x=f2bf(a.x*sc*wa.x); o1.y=f2bf(a.y*sc*wa.y); o1.z=f2bf(a.z*sc*wa.z); o1.w=f2bf(a.w*sc*wa.w);
  o2.x=f2bf(b.x*sc*wb.x); o2.y=f2bf(b.y*sc*wb.y); o2.z=f2bf(b.z*sc*wb.z); o2.w=f2bf(b.w*sc*wb.w);
  ushort4* orow = reinterpret_cast<ushort4*>(out + (size_t)row*HID);
  orow[2*t] = o1; orow[2*t+1] = o2;
}

// ---------------- RoPE tables ----------------
__global__ void k_ropetab(float* __restrict__ cs, float* __restrict__ sn){
  int s = blockIdx.x, j = threadIdx.x;   // 64 threads
  float invf = powf(10000.0f, -(float)j*(1.0f/64.0f));
  float ang = (float)s * invf;
  float c, si;
  sincosf(ang, &si, &c);
  cs[s*64+j] = c; sn[s*64+j] = si;
}

// ---------------- RoPE apply in-place on bf16 [tok][ld] at head offset ----------------
__global__ __launch_bounds__(256) void k_rope(unsigned short* qk, int ld,
                                              const float* __restrict__ cs,
                                              const float* __restrict__ sn, float scale){
  int gid = blockIdx.x*256 + threadIdx.x;
  int j = gid & 63;
  int rh = gid >> 6;               // tok*NH + h
  int tok = rh >> 4, h = rh & 15;
  int s = tok & (SEQL-1);
  unsigned short* base = qk + (size_t)tok*ld + h*HD;
  float c = cs[s*64+j], sv = sn[s*64+j];
  float x1 = bf2f(base[j]), x2 = bf2f(base[j+64]);
  base[j]    = f2bf((x1*c - x2*sv)*scale);
  base[j+64] = f2bf((x2*c + x1*sv)*scale);
}

// ---------------- V transpose: VT[b,h,d,s] <- V[tok][ld] (bf16) ----------------
__global__ __launch_bounds__(256) void k_transpose_v(const unsigned short* __restrict__ V,
                                                     int ld,
                                                     unsigned short* __restrict__ VT){
  __shared__ unsigned short T[64*136];
  int bid = blockIdx.x;
  int sb = bid & 31, h = (bid>>5) & 15, b = bid>>9;
  int t = threadIdx.x;
  int s0 = sb<<6;
  int sl = t>>2, dc = (t&3)<<5;
  const unsigned short* src = V + (size_t)(b*SEQL + s0 + sl)*ld + h*HD + dc;
  #pragma unroll
  for(int p=0;p<4;p++){
    bfx8 v = *reinterpret_cast<const bfx8*>(src + p*8);
    *reinterpret_cast<bfx8*>(&T[sl*136 + dc + p*8]) = v;
  }
  __syncthreads();
  int d = t>>1, sh = (t&1)<<5;
  unsigned short* dst = VT + ((size_t)((b*NH + h)*HD + d))*SEQL + s0 + sh;
  #pragma unroll
  for(int p=0;p<4;p++){
    union { bfx8 v; unsigned short u[8]; } o;
    #pragma unroll
    for(int j=0;j<8;j++) o.u[j] = T[(sh + p*8 + j)*136 + d];
    *reinterpret_cast<bfx8*>(dst + p*8) = o.v;
  }
}

// ---- shared pipeline helpers ----
#define BAR   __builtin_amdgcn_s_barrier()
#define LGKM0 { asm volatile("s_waitcnt lgkmcnt(0)":::"memory"); __builtin_amdgcn_sched_barrier(0); }
#define PRIO1 __builtin_amdgcn_s_setprio(1)
#define PRIO0 __builtin_amdgcn_s_setprio(0)

// ==================== GEMM-D (r13, best on INTERD <=188): 128x128 plain dbuf ==========
// 256 thr = 4 waves (2m x 2n), wave-tile 64x64 (acc 4x4), BK=64, 2-slot LDS (64KB ->
// 2 blk/CU), ONE __syncthreads per K-tile; stage next tile FIRST so the barrier's
// vmcnt(0) drain is covered by this tile's MFMA. No manual waitcnts (compiler emits
// fine-grained lgkmcnt). gll16 + chunk^(row&7) swizzle via pre-swizzled source.
// Band mapping: M=4096 -> 32 m-tiles, 4 per XCD. EPI 0/1/2 as elsewhere.
template<int EPI>
__global__ __launch_bounds__(256) void k_gemmD(const unsigned short* __restrict__ A,
                                               const unsigned short* __restrict__ W,
                                               void* out, const float* __restrict__ resid,
                                               const unsigned short* gbuf,
                                               int M, int N, int K){
  __shared__ unsigned short Alds[2][128*64];
  __shared__ unsigned short Wlds[2][128*64];
  int xcd = blockIdx.x & 7, idx = blockIdx.x >> 3;
  int bm0 = ((xcd<<2) + (idx&3)) << 7;
  int bn0 = (idx>>2) << 7;
  int t = threadIdx.x, w = t>>6, l = t&63, lr = l&15, lg = l>>4;
  int wm = w>>1, wn = w&1;
  int lrow = l>>3, lcs = (l&7) ^ lrow;
  int nt = K >> 6;

  f32x4 z = {0.f,0.f,0.f,0.f};
  f32x4 acc[4][4];
  #pragma unroll
  for(int i=0;i<4;i++){ acc[i][0]=z; acc[i][1]=z; acc[i][2]=z; acc[i][3]=z; }

  #define DSTG(bb, kk) { _Pragma("unroll") for(int p=0;p<4;p++){ \
      int br = (w<<5) + (p<<3); \
      gll16(A + (size_t)(bm0+br+lrow)*K + (kk) + lcs*8, (char*)Alds[bb] + br*128); \
      gll16(W + (size_t)(bn0+br+lrow)*K + (kk) + lcs*8, (char*)Wlds[bb] + br*128); } }

  DSTG(0, 0)
  __syncthreads();

  for(int kt=0; kt<nt; ++kt){
    int cur = kt & 1;
    int kn = (kt+1 < nt) ? ((kt+1)<<6) : 0;   // wrap: stale-but-safe tail staging
    DSTG(cur^1, kn)
    #pragma unroll
    for(int ks=0;ks<2;ks++){
      bfx8 af[4], bfr[4];
      #pragma unroll
      for(int fm=0;fm<4;fm++){
        int row = wm*64 + fm*16 + lr;
        af[fm] = *reinterpret_cast<const bfx8*>((const char*)Alds[cur]
                   + row*128 + ((((ks<<2)+lg) ^ (row&7))<<4));
      }
      #pragma unroll
      for(int fn=0;fn<4;fn++){
        int row = wn*64 + fn*16 + lr;
        bfr[fn] = *reinterpret_cast<const bfx8*>((const char*)Wlds[cur]
                   + row*128 + ((((ks<<2)+lg) ^ (row&7))<<4));
      }
      #pragma unroll
      for(int fm=0;fm<4;fm++)
        #pragma unroll
        for(int fn=0;fn<4;fn++)
          acc[fm][fn] = __builtin_amdgcn_mfma_f32_16x16x32_bf16(af[fm], bfr[fn], acc[fm][fn], 0,0,0);
    }
    __syncthreads();
  }
  #undef DSTG

  // epilogue: row = bm0 + wm*64 + fm*16 + lg*4 + rr ; col = bn0 + wn*64 + fn*16 + lr
  #pragma unroll
  for(int fm=0;fm<4;fm++){
    #pragma unroll
    for(int rr=0;rr<4;rr++){
      int row = bm0 + wm*64 + fm*16 + (lg<<2) + rr;
      #pragma unroll
      for(int fn=0;fn<4;fn++){
        int col = bn0 + wn*64 + fn*16 + lr;
        size_t o = (size_t)row*N + col;
        float v = acc[fm][fn][rr];
        if(EPI==0){
          reinterpret_cast<unsigned short*>(out)[o] = f2bf(v);
        } else if(EPI==1){
          reinterpret_cast<float*>(out)[o] = resid[o] + v;
        } else {
          float g = bf2f(gbuf[o]);
          float sg = g / (1.0f + __expf(-g));
          reinterpret_cast<unsigned short*>(out)[o] = f2bf(sg*v);
        }
      }
    }
  }
}

// ==================== GEMM-N (r10, proven): 256x128 tile, 3-slot — QKV / O / down =====
template<int EPI>
__global__ __launch_bounds__(512, 2) void k_gemmN(const unsigned short* __restrict__ A,
                                                  const unsigned short* __restrict__ W,
                                                  void* out, const float* __restrict__ resid,
                                                  const unsigned short* gbuf,
                                                  int M, int N, int K){
  __shared__ __align__(16) char lds[3*49152];
  int xcd = blockIdx.x & 7, idx = blockIdx.x >> 3;
  int bm0 = ((xcd<<1) + (idx&1)) << 8;      // 16 m-tiles, 2 per XCD
  int bn0 = (idx>>1) << 7;                  // N/128 n-tiles
  int t = threadIdx.x, w = t>>6, l = t&63, lr = l&15, lg = l>>4;
  int wm = w>>1, wn = w&1;
  int lrow = l>>3, lcs = (l&7) ^ lrow;
  int nt = K >> 6;

  f32x4 z = {0.f,0.f,0.f,0.f};
  f32x4 acc[4][4];
  #pragma unroll
  for(int i=0;i<4;i++){ acc[i][0]=z; acc[i][1]=z; acc[i][2]=z; acc[i][3]=z; }

  const unsigned short* sa[4];
  const unsigned short* sb[2];
  #pragma unroll
  for(int p=0;p<4;p++) sa[p] = A + (size_t)(bm0 + p*64 + (w<<3) + lrow)*K + lcs*8;
  #pragma unroll
  for(int p=0;p<2;p++) sb[p] = W + (size_t)(bn0 + p*64 + (w<<3) + lrow)*K + lcs*8;

  #define NSTG_A(Lp, kk) { _Pragma("unroll") for(int p=0;p<4;p++) \
      gll16(sa[p] + (kk), (Lp) + (p*64 + (w<<3))*128); }
  #define NSTG_B(Lp, kk) { _Pragma("unroll") for(int p=0;p<2;p++) \
      gll16(sb[p] + (kk), (Lp) + 32768 + (p*64 + (w<<3))*128); }
  #define NLD(Lc, ks) { \
    _Pragma("unroll") for(int i=0;i<4;i++){ int row = (wm<<6) + i*16 + lr; \
      af[i] = *reinterpret_cast<const bfx8*>((Lc) + row*128 + ((((ks<<2)+lg)^(row&7))<<4)); } \
    _Pragma("unroll") for(int j=0;j<4;j++){ int row = (wn<<6) + j*16 + lr; \
      bq[j] = *reinterpret_cast<const bfx8*>((Lc) + 32768 + row*128 + ((((ks<<2)+lg)^(row&7))<<4)); } }
  #define NMM { _Pragma("unroll") for(int i=0;i<4;i++) \
                _Pragma("unroll") for(int j=0;j<4;j++) \
      acc[i][j] = __builtin_amdgcn_mfma_f32_16x16x32_bf16(af[i], bq[j], acc[i][j], 0,0,0); }

  char* S0 = lds; char* S1 = lds + 49152; char* S2 = lds + 98304;
  NSTG_A(S0, 0) NSTG_B(S0, 0) NSTG_A(S1, 64) NSTG_B(S1, 64)
  asm volatile("s_waitcnt vmcnt(6)":::"memory");
  BAR;

  bfx8 af[4], bq[4];
  for(int kt=0; kt<nt; ++kt){
    int k2 = (kt+2 < nt) ? ((kt+2)<<6) : 0;   // wrap: stale-but-safe tail staging
    NLD(S0, 0)
    NSTG_A(S2, k2)
    BAR; LGKM0 PRIO1; NMM PRIO0; BAR;
    NLD(S0, 1)
    NSTG_B(S2, k2)
    BAR; LGKM0 PRIO1; NMM PRIO0;
    asm volatile("s_waitcnt vmcnt(6)":::"memory");
    BAR;
    char* tmp = S0; S0 = S1; S1 = S2; S2 = tmp;
  }
  #undef NSTG_A
  #undef NSTG_B
  #undef NLD
  #undef NMM

  #pragma unroll
  for(int fm=0;fm<4;fm++){
    #pragma unroll
    for(int rr=0;rr<4;rr++){
      int row = bm0 + (wm<<6) + fm*16 + (lg<<2) + rr;
      #pragma unroll
      for(int fn=0;fn<4;fn++){
        int col = bn0 + (wn<<6) + fn*16 + lr;
        size_t o = (size_t)row*N + col;
        float v = acc[fm][fn][rr];
        if(EPI==0){
          reinterpret_cast<unsigned short*>(out)[o] = f2bf(v);
        } else if(EPI==1){
          reinterpret_cast<float*>(out)[o] = resid[o] + v;
        } else {
          float g = bf2f(gbuf[o]);
          float sg = g / (1.0f + __expf(-g));
          reinterpret_cast<unsigned short*>(out)[o] = f2bf(sg*v);
        }
      }
    }
  }
}

// ---------------- Flash attention, causal (unchanged from rounds 4-14) ----------------
__global__ __launch_bounds__(256) void k_attn(const unsigned short* __restrict__ Q,
                                              const unsigned short* __restrict__ Kb,
                                              int ldqk,
                                              const unsigned short* __restrict__ VT,
                                              unsigned short* __restrict__ O){
  __shared__ unsigned short Klds[64*128];
  __shared__ unsigned short Vlds[128*64];
  __shared__ unsigned short Plds[4][16*72];

  int bid = blockIdx.x;
  int xcd = bid & 7, idx = bid >> 3;
  int bh = xcd*4 + (idx & 3);
  int qt = 31 - (idx >> 2);
  int h = bh & 15, b = bh >> 4;
  int q0 = qt << 6;
  int t = threadIdx.x, w = t>>6, l = t&63, lr = l&15, lg = l>>4;
  int q0w = q0 + (w<<4);

  bfx8 qf[4];
  const unsigned short* qrow = Q + (size_t)(b*SEQL + q0w + lr)*ldqk + h*HD;
  #pragma unroll
  for(int ds=0;ds<4;ds++) qf[ds] = *reinterpret_cast<const bfx8*>(qrow + ds*32 + lg*8);

  f32x4 z = {0.f,0.f,0.f,0.f};
  f32x4 oacc[8];
  #pragma unroll
  for(int i=0;i<8;i++) oacc[i] = z;
  float m_run = -1e30f, l_run = 0.f;

  int srow = t>>3, sch = t&7;
  int ntile = qt + 1;
  for(int tl=0; tl<ntile; ++tl){
    int k0 = tl << 6;
    __syncthreads();
    #pragma unroll
    for(int pr=0;pr<2;pr++){
      int row = srow + (pr<<5);
      const unsigned short* ks = Kb + (size_t)(b*SEQL + k0 + row)*ldqk + h*HD;
      #pragma unroll
      for(int pc=0;pc<2;pc++){
        int cl = sch + (pc<<3);
        *reinterpret_cast<bfx8*>((char*)Klds + row*256 + ((cl ^ (row&7))<<4)) =
            *reinterpret_cast<const bfx8*>(ks + cl*8);
      }
    }
    #pragma unroll
    for(int pr=0;pr<4;pr++){
      int row = srow + (pr<<5);
      const unsigned short* vs = VT + ((size_t)((b*NH + h)*HD + row))*SEQL + k0;
      *reinterpret_cast<bfx8*>((char*)Vlds + row*128 + ((sch ^ (row&7))<<4)) =
          *reinterpret_cast<const bfx8*>(vs + sch*8);
    }
    __syncthreads();

    f32x4 sAcc[4];
    sAcc[0]=z; sAcc[1]=z; sAcc[2]=z; sAcc[3]=z;
    #pragma unroll
    for(int ds=0;ds<4;ds++){
      int cha = (ds<<2) + lg;
      #pragma unroll
      for(int kg=0;kg<4;kg++){
        int row = (kg<<4) + lr;
        bfx8 ka = *reinterpret_cast<const bfx8*>((char*)Klds + row*256 + ((cha ^ (row&7))<<4));
        sAcc[kg] = __builtin_amdgcn_mfma_f32_16x16x32_bf16(ka, qf[ds], sAcc[kg], 0,0,0);
      }
    }
    int qg = q0w + lr;
    float p[16];
    float mx = -1e30f;
    #pragma unroll
    for(int kg=0;kg<4;kg++){
      #pragma unroll
      for(int r=0;r<4;r++){
        int kk = k0 + (kg<<4) + (lg<<2) + r;
        float v = (kk <= qg) ? sAcc[kg][r] : -1e30f;
        p[kg*4+r] = v; mx = fmaxf(mx, v);
      }
    }
    mx = fmaxf(mx, __shfl_xor(mx,16));
    mx = fmaxf(mx, __shfl_xor(mx,32));
    float m_new = fmaxf(m_run, mx);
    float fac = __expf(m_run - m_new);
    float ts = 0.f;
    #pragma unroll
    for(int i=0;i<16;i++){ p[i] = __expf(p[i]-m_new); ts += p[i]; }
    ts += __shfl_xor(ts,16); ts += __shfl_xor(ts,32);
    l_run = l_run*fac + ts;
    m_run = m_new;
    char* pb = (char*)&Plds[w][0] + lr*144 + lg*8;
    #pragma unroll
    for(int kg=0;kg<4;kg++){
      unsigned pa = (unsigned)f2bf(p[kg*4+0]) | ((unsigned)f2bf(p[kg*4+1])<<16);
      unsigned pc = (unsigned)f2bf(p[kg*4+2]) | ((unsigned)f2bf(p[kg*4+3])<<16);
      *reinterpret_cast<uint2*>(pb + kg*32) = make_uint2(pa, pc);
    }
    float facr[4];
    #pragma unroll
    for(int r=0;r<4;r++) facr[r] = __shfl(fac, (lg<<2)+r);
    #pragma unroll
    for(int db=0;db<8;db++){
      f32x4 o = oacc[db];
      o[0]*=facr[0]; o[1]*=facr[1]; o[2]*=facr[2]; o[3]*=facr[3];
      oacc[db] = o;
    }
    __syncthreads();
    #pragma unroll
    for(int kh=0;kh<2;kh++){
      bfx8 pf = *reinterpret_cast<const bfx8*>((char*)&Plds[w][0] + lr*144 + kh*64 + lg*16);
      #pragma unroll
      for(int db=0;db<8;db++){
        int row = (db<<4) + lr;
        int lc = (kh<<2) + lg;
        bfx8 vf = *reinterpret_cast<const bfx8*>((char*)Vlds + row*128 + ((lc ^ (row&7))<<4));
        oacc[db] = __builtin_amdgcn_mfma_f32_16x16x32_bf16(pf, vf, oacc[db], 0,0,0);
      }
    }
  }
  float lsr[4];
  #pragma unroll
  for(int r=0;r<4;r++) lsr[r] = 1.0f / __shfl(l_run, (lg<<2)+r);
  #pragma unroll
  for(int db=0;db<8;db++){
    #pragma unroll
    for(int r=0;r<4;r++){
      int row = q0w + (lg<<2) + r;
      O[((size_t)((b*SEQL + row)*NH) + h)*HD + (db<<4) + lr] = f2bf(oacc[db][r]*lsr[r]);
    }
  }
}

// ---------------- host launcher (r10 plan, 145MB; gate/up moved to gemmD) -------------
extern "C" void kernel_launch(void* const* d_in, const int* in_sizes, int n_in,
                              void* d_out, int out_size, void* d_ws, size_t ws_size,
                              hipStream_t stream){
  const float* x   = (const float*)d_in[0];
  const float* anw = (const float*)d_in[1];
  const float* qw  = (const float*)d_in[2];
  const float* kw  = (const float*)d_in[3];
  const float* vw  = (const float*)d_in[4];
  const float* ow  = (const float*)d_in[5];
  const float* fnw = (const float*)d_in[6];
  const float* gw  = (const float*)d_in[7];
  const float* uw  = (const float*)d_in[8];
  const float* dw  = (const float*)d_in[9];
  float* out = (float*)d_out;

  char* ws = (char*)d_ws;
  size_t off = 0;
  auto alloc = [&](size_t bytes)->char*{ char* p = ws + off; off += (bytes + 255) & ~(size_t)255; return p; };
  unsigned short* Wbuf = (unsigned short*)alloc((size_t)INTERD*HID*2);     // 32 MB
  unsigned short* hb   = (unsigned short*)alloc((size_t)NTOK*HID*2);       // 16 MB
  unsigned short* qkvb = (unsigned short*)alloc((size_t)NTOK*3*HID*2);     // 48 MB
  unsigned short* aob  = (unsigned short*)alloc((size_t)NTOK*HID*2);       // 16 MB
  float*          x1   = (float*)alloc((size_t)NTOK*HID*4);                // 32 MB
  float*          cosb = (float*)alloc((size_t)SEQL*64*4);
  float*          sinb = (float*)alloc((size_t)SEQL*64*4);
  unsigned short* gb   = qkvb;                // 64 MB overlay (qkvb+aob), dead after O-proj
  unsigned short* VT   = (unsigned short*)x1; // 16 MB overlay: x1 written only after attn
  if(ws_size < off){ k_sentinel<<<1,1,0,stream>>>(out); return; }

  k_ropetab<<<SEQL, 64, 0, stream>>>(cosb, sinb);

  // ---- attention sublayer ----
  k_rmsnorm<<<NTOK, 256, 0, stream>>>(x, anw, hb);
  k_cvt<<<HID*HID/1024, 256, 0, stream>>>(qw, Wbuf,             HID*HID/4);
  k_cvt<<<HID*HID/1024, 256, 0, stream>>>(kw, Wbuf +   HID*HID, HID*HID/4);
  k_cvt<<<HID*HID/1024, 256, 0, stream>>>(vw, Wbuf + 2*HID*HID, HID*HID/4);
  k_gemmN<0><<<16*(3*HID/128), 512, 0, stream>>>(hb, Wbuf, qkvb, nullptr, nullptr, NTOK, 3*HID, HID);  // 768
  k_rope<<<(NTOK*NH*64)/256, 256, 0, stream>>>(qkvb,        3*HID, cosb, sinb, 0.08838834764831845f);
  k_rope<<<(NTOK*NH*64)/256, 256, 0, stream>>>(qkvb +  HID, 3*HID, cosb, sinb, 1.0f);
  k_transpose_v<<<NBATCH*NH*(SEQL/64), 256, 0, stream>>>(qkvb + 2*HID, 3*HID, VT);
  k_attn<<<(SEQL/64)*NBATCH*NH, 256, 0, stream>>>(qkvb, qkvb + HID, 3*HID, VT, aob);
  k_cvt<<<HID*HID/1024, 256, 0, stream>>>(ow, Wbuf, HID*HID/4);
  k_gemmN<1><<<16*(HID/128), 512, 0, stream>>>(aob, Wbuf, x1, x, nullptr, NTOK, HID, HID);             // 256

  // ---- MLP sublayer ----
  k_rmsnorm<<<NTOK, 256, 0, stream>>>(x1, fnw, hb);
  k_cvt<<<INTERD*HID/1024, 256, 0, stream>>>(gw, Wbuf, INTERD*HID/4);
  k_gemmD<0><<<(NTOK/128)*(INTERD/128), 256, 0, stream>>>(hb, Wbuf, gb, nullptr, nullptr, NTOK, INTERD, HID); // 2048
  k_cvt<<<INTERD*HID/1024, 256, 0, stream>>>(uw, Wbuf, INTERD*HID/4);
  k_gemmD<2><<<(NTOK/128)*(INTERD/128), 256, 0, stream>>>(hb, Wbuf, gb, nullptr, gb, NTOK, INTERD, HID);      // 2048
  k_cvt<<<INTERD*HID/1024, 256, 0, stream>>>(dw, Wbuf, INTERD*HID/4);
  k_gemmN<1><<<16*(HID/128), 512, 0, stream>>>(gb, Wbuf, out, x1, nullptr, NTOK, HID, INTERD);                // 256
}

// Round 16
// 852.629 us; speedup vs baseline: 1.1875x; 1.0577x over previous
//
#include <hip/hip_runtime.h>
#include <math.h>

#define HID 2048
#define NH 16
#define HD 128
#define INTERD 8192
#define SEQL 2048
#define NBATCH 2
#define NTOK (NBATCH*SEQL)

typedef float f32x4 __attribute__((ext_vector_type(4)));
typedef __bf16 bfx8 __attribute__((ext_vector_type(8)));

__device__ __forceinline__ float bf2f(unsigned short u){
  union { float f; unsigned v; } c; c.v = ((unsigned)u)<<16; return c.f;
}
__device__ __forceinline__ unsigned short f2bf(float f){
  union { float f; unsigned v; } c; c.f = f;
  unsigned r = c.v + 0x7FFFu + ((c.v>>16)&1u);   // RNE
  return (unsigned short)(r>>16);
}

// async global->LDS, 16B/lane; LDS dest = wave-uniform base + lane*16 (proven r3-r15).
__device__ __forceinline__ void gll16(const unsigned short* g, void* l){
  __builtin_amdgcn_global_load_lds(
      (const __attribute__((address_space(1))) unsigned int*)(size_t)(const void*)g,
      (__attribute__((address_space(3))) unsigned int*)(unsigned int)(size_t)l,
      16, 0, 0);
}

__global__ void k_sentinel(float* out){ out[0] = 1.0e9f; }

// ---------------- fp32 -> bf16 conversion (weights) ----------------
__global__ __launch_bounds__(256) void k_cvt(const float* __restrict__ in,
                                             unsigned short* __restrict__ out, int n4){
  int i = blockIdx.x*256 + threadIdx.x;
  if(i >= n4) return;
  float4 v = reinterpret_cast<const float4*>(in)[i];
  ushort4 o;
  o.x = f2bf(v.x); o.y = f2bf(v.y); o.z = f2bf(v.z); o.w = f2bf(v.w);
  reinterpret_cast<ushort4*>(out)[i] = o;
}

// ---------------- RMSNorm (fp32 in) -> bf16 out ----------------
__global__ __launch_bounds__(256) void k_rmsnorm(const float* __restrict__ x,
                                                 const float* __restrict__ w,
                                                 unsigned short* __restrict__ out){
  int row = blockIdx.x, t = threadIdx.x;
  const float4* xr = reinterpret_cast<const float4*>(x + (size_t)row*HID);
  float4 a = xr[2*t], b = xr[2*t+1];
  float ss = a.x*a.x+a.y*a.y+a.z*a.z+a.w*a.w + b.x*b.x+b.y*b.y+b.z*b.z+b.w*b.w;
  #pragma unroll
  for(int o=1;o<64;o<<=1) ss += __shfl_xor(ss, o);
  __shared__ float red[4];
  if((t&63)==0) red[t>>6] = ss;
  __syncthreads();
  float sc = rsqrtf((red[0]+red[1]+red[2]+red[3])*(1.0f/HID) + 1e-6f);
  const float4* wr = reinterpret_cast<const float4*>(w);
  float4 wa = wr[2*t], wb = wr[2*t+1];
  ushort4 o1, o2;
  o1.x=f2bf(a.x*sc*wa.x); o1.y=f2bf(a.y*sc*wa.y); o1.z=f2bf(a.z*sc*wa.z); o1.w=f2bf(a.w*sc*wa.w);
  o2.x=f2bf(b.x*sc*wb.x); o2.y=f2bf(b.y*sc*wb.y); o2.z=f2bf(b.z*sc*wb.z); o2.w=f2bf(b.w*sc*wb.w);
  ushort4* orow = reinterpret_cast<ushort4*>(out + (size_t)row*HID);
  orow[2*t] = o1; orow[2*t+1] = o2;
}

// ---------------- RoPE tables ----------------
__global__ void k_ropetab(float* __restrict__ cs, float* __restrict__ sn){
  int s = blockIdx.x, j = threadIdx.x;   // 64 threads
  float invf = powf(10000.0f, -(float)j*(1.0f/64.0f));
  float ang = (float)s * invf;
  float c, si;
  sincosf(ang, &si, &c);
  cs[s*64+j] = c; sn[s*64+j] = si;
}

// ---------------- RoPE apply in-place on bf16 [tok][ld] at head offset ----------------
__global__ __launch_bounds__(256) void k_rope(unsigned short* qk, int ld,
                                              const float* __restrict__ cs,
                                              const float* __restrict__ sn, float scale){
  int gid = blockIdx.x*256 + threadIdx.x;
  int j = gid & 63;
  int rh = gid >> 6;               // tok*NH + h
  int tok = rh >> 4, h = rh & 15;
  int s = tok & (SEQL-1);
  unsigned short* base = qk + (size_t)tok*ld + h*HD;
  float c = cs[s*64+j], sv = sn[s*64+j];
  float x1 = bf2f(base[j]), x2 = bf2f(base[j+64]);
  base[j]    = f2bf((x1*c - x2*sv)*scale);
  base[j+64] = f2bf((x2*c + x1*sv)*scale);
}

// ---------------- V transpose: VT[b,h,d,s] <- V[tok][ld] (bf16) ----------------
__global__ __launch_bounds__(256) void k_transpose_v(const unsigned short* __restrict__ V,
                                                     int ld,
                                                     unsigned short* __restrict__ VT){
  __shared__ unsigned short T[64*136];
  int bid = blockIdx.x;
  int sb = bid & 31, h = (bid>>5) & 15, b = bid>>9;
  int t = threadIdx.x;
  int s0 = sb<<6;
  int sl = t>>2, dc = (t&3)<<5;
  const unsigned short* src = V + (size_t)(b*SEQL + s0 + sl)*ld + h*HD + dc;
  #pragma unroll
  for(int p=0;p<4;p++){
    bfx8 v = *reinterpret_cast<const bfx8*>(src + p*8);
    *reinterpret_cast<bfx8*>(&T[sl*136 + dc + p*8]) = v;
  }
  __syncthreads();
  int d = t>>1, sh = (t&1)<<5;
  unsigned short* dst = VT + ((size_t)((b*NH + h)*HD + d))*SEQL + s0 + sh;
  #pragma unroll
  for(int p=0;p<4;p++){
    union { bfx8 v; unsigned short u[8]; } o;
    #pragma unroll
    for(int j=0;j<8;j++) o.u[j] = T[(sh + p*8 + j)*136 + d];
    *reinterpret_cast<bfx8*>(dst + p*8) = o.v;
  }
}

// ---- shared pipeline helpers ----
#define BAR   __builtin_amdgcn_s_barrier()
#define LGKM0 { asm volatile("s_waitcnt lgkmcnt(0)":::"memory"); __builtin_amdgcn_sched_barrier(0); }
#define PRIO1 __builtin_amdgcn_s_setprio(1)
#define PRIO0 __builtin_amdgcn_s_setprio(0)

// ==================== GEMM 8-phase (r9, proven 190us on INTERD): gate / up ============
// BM=BN=256, BK=64; 512 thr = 8 waves (2M x 4N); wave-tile 128x64 (acc 8x4).
// 2 LDS slots (even/odd K-tile). Counted vmcnt at ph3 (4) and ph7 (8), never 0.
template<int EPI>
__global__ __launch_bounds__(512, 2) void k_gemm8(const unsigned short* __restrict__ A,
                                                  const unsigned short* __restrict__ W,
                                                  void* out, const float* __restrict__ resid,
                                                  const unsigned short* gbuf,
                                                  int M, int N, int K){
  __shared__ __align__(16) char lds[2][65536];   // slot: A[256][64]@0, B[256][64]@32768
  int xcd = blockIdx.x & 7, idx = blockIdx.x >> 3;
  int bm0 = (idx & 15) << 8;
  int bn0 = ((idx >> 4) + xcd*(N >> 11)) << 8;
  int t = threadIdx.x, w = t>>6, l = t&63, lr = l&15, lg = l>>4;
  int wm = w>>2, wn = w&3;
  int lrow = l>>3, lcs = (l&7) ^ lrow;
  int nt = K >> 7;

  f32x4 z = {0.f,0.f,0.f,0.f};
  f32x4 acc[8][4];
  #pragma unroll
  for(int i=0;i<8;i++){ acc[i][0]=z; acc[i][1]=z; acc[i][2]=z; acc[i][3]=z; }

  const unsigned short* sa[2][2];
  const unsigned short* sb[2][2];
  #pragma unroll
  for(int h=0;h<2;h++)
    #pragma unroll
    for(int p=0;p<2;p++){
      int r = h*128 + p*64 + (w<<3) + lrow;
      sa[h][p] = A + (size_t)(bm0 + r)*K + lcs*8;
      sb[h][p] = W + (size_t)(bn0 + r)*K + lcs*8;
    }

  #define STG_A(s, h, kk) { \
    _Pragma("unroll") for(int p=0;p<2;p++){ \
      int rb = ((h)*128 + p*64 + (w<<3))*128; \
      gll16(sa[h][p] + (kk), lds[s] + rb); } }
  #define STG_B(s, h, kk) { \
    _Pragma("unroll") for(int p=0;p<2;p++){ \
      int rb = ((h)*128 + p*64 + (w<<3))*128; \
      gll16(sb[h][p] + (kk), lds[s] + 32768 + rb); } }
  #define LD_AF(dst, s, fm0) { \
    _Pragma("unroll") for(int i=0;i<4;i++){ \
      int row = wm*128 + ((fm0)+i)*16 + lr; \
      _Pragma("unroll") for(int ks=0;ks<2;ks++) \
        dst[i][ks] = *reinterpret_cast<const bfx8*>(lds[s] + row*128 + ((((ks<<2)+lg)^(row&7))<<4)); } }
  #define LD_BF(dst, s, fn0) { \
    _Pragma("unroll") for(int i=0;i<2;i++){ \
      int row = wn*64 + ((fn0)+i)*16 + lr; \
      _Pragma("unroll") for(int ks=0;ks<2;ks++) \
        dst[i][ks] = *reinterpret_cast<const bfx8*>(lds[s] + 32768 + row*128 + ((((ks<<2)+lg)^(row&7))<<4)); } }
  #define MM(qm, qn, AF, BF) { \
    _Pragma("unroll") for(int i=0;i<4;i++) \
    _Pragma("unroll") for(int j=0;j<2;j++) \
    _Pragma("unroll") for(int ks=0;ks<2;ks++) \
      acc[(qm)*4+i][(qn)*2+j] = __builtin_amdgcn_mfma_f32_16x16x32_bf16(AF[i][ks], BF[j][ks], acc[(qm)*4+i][(qn)*2+j], 0,0,0); }

  STG_A(0,0,0)  STG_B(0,0,0)  STG_A(0,1,0)  STG_B(0,1,0)
  STG_A(1,0,64) STG_B(1,0,64) STG_A(1,1,64) STG_B(1,1,64)
  asm volatile("s_waitcnt vmcnt(8)":::"memory");
  BAR;

  bfx8 afl[4][2], afh[4][2], bfl[2][2], bfh[2][2];

  for(int it=0; it<nt; ++it){
    int k2 = (2*it+2 < 2*nt) ? ((2*it+2)<<6) : 0;
    int k3 = (2*it+3 < 2*nt) ? ((2*it+3)<<6) : 64;
    LD_AF(afl,0,0) LD_BF(bfl,0,0)
    asm volatile("s_waitcnt lgkmcnt(8)":::"memory");
    BAR; LGKM0 PRIO1; MM(0,0,afl,bfl) PRIO0; BAR;
    LD_BF(bfh,0,2)
    BAR; LGKM0 PRIO1; MM(0,1,afl,bfh) PRIO0; BAR;
    LD_AF(afh,0,4)
    BAR; LGKM0 PRIO1; MM(1,0,afh,bfl) PRIO0; BAR;
    STG_A(0,0,k2) STG_B(0,0,k2)
    BAR; PRIO1; MM(1,1,afh,bfh) PRIO0;
    asm volatile("s_waitcnt vmcnt(4)":::"memory");
    BAR;
    LD_AF(afl,1,0) LD_BF(bfl,1,0)
    STG_A(0,1,k2) STG_B(0,1,k2)
    asm volatile("s_waitcnt lgkmcnt(8)":::"memory");
    BAR; LGKM0 PRIO1; MM(0,0,afl,bfl) PRIO0; BAR;
    LD_BF(bfh,1,2)
    BAR; LGKM0 PRIO1; MM(0,1,afl,bfh) PRIO0; BAR;
    LD_AF(afh,1,4)
    STG_B(1,0,k3) STG_B(1,1,k3)
    BAR; LGKM0 PRIO1; MM(1,0,afh,bfl) PRIO0; BAR;
    STG_A(1,0,k3) STG_A(1,1,k3)
    BAR; PRIO1; MM(1,1,afh,bfh) PRIO0;
    asm volatile("s_waitcnt vmcnt(8)":::"memory");
    BAR;
  }
  #undef STG_A
  #undef STG_B
  #undef LD_AF
  #undef LD_BF
  #undef MM

  #pragma unroll
  for(int fm=0;fm<8;fm++){
    #pragma unroll
    for(int rr=0;rr<4;rr++){
      int row = bm0 + wm*128 + fm*16 + (lg<<2) + rr;
      #pragma unroll
      for(int fn=0;fn<4;fn++){
        int col = bn0 + wn*64 + fn*16 + lr;
        size_t o = (size_t)row*N + col;
        float v = acc[fm][fn][rr];
        if(EPI==0){
          reinterpret_cast<unsigned short*>(out)[o] = f2bf(v);
        } else if(EPI==1){
          reinterpret_cast<float*>(out)[o] = resid[o] + v;
        } else {
          float g = bf2f(gbuf[o]);
          float sg = g / (1.0f + __expf(-g));
          reinterpret_cast<unsigned short*>(out)[o] = f2bf(sg*v);
        }
      }
    }
  }
}

// ==================== GEMM-N (r10, proven): 256x128 tile, 3-slot — QKV / O / down =====
template<int EPI>
__global__ __launch_bounds__(512, 2) void k_gemmN(const unsigned short* __restrict__ A,
                                                  const unsigned short* __restrict__ W,
                                                  void* out, const float* __restrict__ resid,
                                                  const unsigned short* gbuf,
                                                  int M, int N, int K){
  __shared__ __align__(16) char lds[3*49152];
  int xcd = blockIdx.x & 7, idx = blockIdx.x >> 3;
  int bm0 = ((xcd<<1) + (idx&1)) << 8;      // 16 m-tiles, 2 per XCD
  int bn0 = (idx>>1) << 7;                  // N/128 n-tiles
  int t = threadIdx.x, w = t>>6, l = t&63, lr = l&15, lg = l>>4;
  int wm = w>>1, wn = w&1;
  int lrow = l>>3, lcs = (l&7) ^ lrow;
  int nt = K >> 6;

  f32x4 z = {0.f,0.f,0.f,0.f};
  f32x4 acc[4][4];
  #pragma unroll
  for(int i=0;i<4;i++){ acc[i][0]=z; acc[i][1]=z; acc[i][2]=z; acc[i][3]=z; }

  const unsigned short* sa[4];
  const unsigned short* sb[2];
  #pragma unroll
  for(int p=0;p<4;p++) sa[p] = A + (size_t)(bm0 + p*64 + (w<<3) + lrow)*K + lcs*8;
  #pragma unroll
  for(int p=0;p<2;p++) sb[p] = W + (size_t)(bn0 + p*64 + (w<<3) + lrow)*K + lcs*8;

  #define NSTG_A(Lp, kk) { _Pragma("unroll") for(int p=0;p<4;p++) \
      gll16(sa[p] + (kk), (Lp) + (p*64 + (w<<3))*128); }
  #define NSTG_B(Lp, kk) { _Pragma("unroll") for(int p=0;p<2;p++) \
      gll16(sb[p] + (kk), (Lp) + 32768 + (p*64 + (w<<3))*128); }
  #define NLD(Lc, ks) { \
    _Pragma("unroll") for(int i=0;i<4;i++){ int row = (wm<<6) + i*16 + lr; \
      af[i] = *reinterpret_cast<const bfx8*>((Lc) + row*128 + ((((ks<<2)+lg)^(row&7))<<4)); } \
    _Pragma("unroll") for(int j=0;j<4;j++){ int row = (wn<<6) + j*16 + lr; \
      bq[j] = *reinterpret_cast<const bfx8*>((Lc) + 32768 + row*128 + ((((ks<<2)+lg)^(row&7))<<4)); } }
  #define NMM { _Pragma("unroll") for(int i=0;i<4;i++) \
                _Pragma("unroll") for(int j=0;j<4;j++) \
      acc[i][j] = __builtin_amdgcn_mfma_f32_16x16x32_bf16(af[i], bq[j], acc[i][j], 0,0,0); }

  char* S0 = lds; char* S1 = lds + 49152; char* S2 = lds + 98304;
  NSTG_A(S0, 0) NSTG_B(S0, 0) NSTG_A(S1, 64) NSTG_B(S1, 64)
  asm volatile("s_waitcnt vmcnt(6)":::"memory");
  BAR;

  bfx8 af[4], bq[4];
  for(int kt=0; kt<nt; ++kt){
    int k2 = (kt+2 < nt) ? ((kt+2)<<6) : 0;   // wrap: stale-but-safe tail staging
    NLD(S0, 0)
    NSTG_A(S2, k2)
    BAR; LGKM0 PRIO1; NMM PRIO0; BAR;
    NLD(S0, 1)
    NSTG_B(S2, k2)
    BAR; LGKM0 PRIO1; NMM PRIO0;
    asm volatile("s_waitcnt vmcnt(6)":::"memory");
    BAR;
    char* tmp = S0; S0 = S1; S1 = S2; S2 = tmp;
  }
  #undef NSTG_A
  #undef NSTG_B
  #undef NLD
  #undef NMM

  #pragma unroll
  for(int fm=0;fm<4;fm++){
    #pragma unroll
    for(int rr=0;rr<4;rr++){
      int row = bm0 + (wm<<6) + fm*16 + (lg<<2) + rr;
      #pragma unroll
      for(int fn=0;fn<4;fn++){
        int col = bn0 + (wn<<6) + fn*16 + lr;
        size_t o = (size_t)row*N + col;
        float v = acc[fm][fn][rr];
        if(EPI==0){
          reinterpret_cast<unsigned short*>(out)[o] = f2bf(v);
        } else if(EPI==1){
          reinterpret_cast<float*>(out)[o] = resid[o] + v;
        } else {
          float g = bf2f(gbuf[o]);
          float sg = g / (1.0f + __expf(-g));
          reinterpret_cast<unsigned short*>(out)[o] = f2bf(sg*v);
        }
      }
    }
  }
}

// ---------------- Flash attention, causal (unchanged from rounds 4-15) ----------------
__global__ __launch_bounds__(256) void k_attn(const unsigned short* __restrict__ Q,
                                              const unsigned short* __restrict__ Kb,
                                              int ldqk,
                                              const unsigned short* __restrict__ VT,
                                              unsigned short* __restrict__ O){
  __shared__ unsigned short Klds[64*128];
  __shared__ unsigned short Vlds[128*64];
  __shared__ unsigned short Plds[4][16*72];

  int bid = blockIdx.x;
  int xcd = bid & 7, idx = bid >> 3;
  int bh = xcd*4 + (idx & 3);
  int qt = 31 - (idx >> 2);
  int h = bh & 15, b = bh >> 4;
  int q0 = qt << 6;
  int t = threadIdx.x, w = t>>6, l = t&63, lr = l&15, lg = l>>4;
  int q0w = q0 + (w<<4);

  bfx8 qf[4];
  const unsigned short* qrow = Q + (size_t)(b*SEQL + q0w + lr)*ldqk + h*HD;
  #pragma unroll
  for(int ds=0;ds<4;ds++) qf[ds] = *reinterpret_cast<const bfx8*>(qrow + ds*32 + lg*8);

  f32x4 z = {0.f,0.f,0.f,0.f};
  f32x4 oacc[8];
  #pragma unroll
  for(int i=0;i<8;i++) oacc[i] = z;
  float m_run = -1e30f, l_run = 0.f;

  int srow = t>>3, sch = t&7;
  int ntile = qt + 1;
  for(int tl=0; tl<ntile; ++tl){
    int k0 = tl << 6;
    __syncthreads();
    #pragma unroll
    for(int pr=0;pr<2;pr++){
      int row = srow + (pr<<5);
      const unsigned short* ks = Kb + (size_t)(b*SEQL + k0 + row)*ldqk + h*HD;
      #pragma unroll
      for(int pc=0;pc<2;pc++){
        int cl = sch + (pc<<3);
        *reinterpret_cast<bfx8*>((char*)Klds + row*256 + ((cl ^ (row&7))<<4)) =
            *reinterpret_cast<const bfx8*>(ks + cl*8);
      }
    }
    #pragma unroll
    for(int pr=0;pr<4;pr++){
      int row = srow + (pr<<5);
      const unsigned short* vs = VT + ((size_t)((b*NH + h)*HD + row))*SEQL + k0;
      *reinterpret_cast<bfx8*>((char*)Vlds + row*128 + ((sch ^ (row&7))<<4)) =
          *reinterpret_cast<const bfx8*>(vs + sch*8);
    }
    __syncthreads();

    f32x4 sAcc[4];
    sAcc[0]=z; sAcc[1]=z; sAcc[2]=z; sAcc[3]=z;
    #pragma unroll
    for(int ds=0;ds<4;ds++){
      int cha = (ds<<2) + lg;
      #pragma unroll
      for(int kg=0;kg<4;kg++){
        int row = (kg<<4) + lr;
        bfx8 ka = *reinterpret_cast<const bfx8*>((char*)Klds + row*256 + ((cha ^ (row&7))<<4));
        sAcc[kg] = __builtin_amdgcn_mfma_f32_16x16x32_bf16(ka, qf[ds], sAcc[kg], 0,0,0);
      }
    }
    int qg = q0w + lr;
    float p[16];
    float mx = -1e30f;
    #pragma unroll
    for(int kg=0;kg<4;kg++){
      #pragma unroll
      for(int r=0;r<4;r++){
        int kk = k0 + (kg<<4) + (lg<<2) + r;
        float v = (kk <= qg) ? sAcc[kg][r] : -1e30f;
        p[kg*4+r] = v; mx = fmaxf(mx, v);
      }
    }
    mx = fmaxf(mx, __shfl_xor(mx,16));
    mx = fmaxf(mx, __shfl_xor(mx,32));
    float m_new = fmaxf(m_run, mx);
    float fac = __expf(m_run - m_new);
    float ts = 0.f;
    #pragma unroll
    for(int i=0;i<16;i++){ p[i] = __expf(p[i]-m_new); ts += p[i]; }
    ts += __shfl_xor(ts,16); ts += __shfl_xor(ts,32);
    l_run = l_run*fac + ts;
    m_run = m_new;
    char* pb = (char*)&Plds[w][0] + lr*144 + lg*8;
    #pragma unroll
    for(int kg=0;kg<4;kg++){
      unsigned pa = (unsigned)f2bf(p[kg*4+0]) | ((unsigned)f2bf(p[kg*4+1])<<16);
      unsigned pc = (unsigned)f2bf(p[kg*4+2]) | ((unsigned)f2bf(p[kg*4+3])<<16);
      *reinterpret_cast<uint2*>(pb + kg*32) = make_uint2(pa, pc);
    }
    float facr[4];
    #pragma unroll
    for(int r=0;r<4;r++) facr[r] = __shfl(fac, (lg<<2)+r);
    #pragma unroll
    for(int db=0;db<8;db++){
      f32x4 o = oacc[db];
      o[0]*=facr[0]; o[1]*=facr[1]; o[2]*=facr[2]; o[3]*=facr[3];
      oacc[db] = o;
    }
    __syncthreads();
    #pragma unroll
    for(int kh=0;kh<2;kh++){
      bfx8 pf = *reinterpret_cast<const bfx8*>((char*)&Plds[w][0] + lr*144 + kh*64 + lg*16);
      #pragma unroll
      for(int db=0;db<8;db++){
        int row = (db<<4) + lr;
        int lc = (kh<<2) + lg;
        bfx8 vf = *reinterpret_cast<const bfx8*>((char*)Vlds + row*128 + ((lc ^ (row&7))<<4));
        oacc[db] = __builtin_amdgcn_mfma_f32_16x16x32_bf16(pf, vf, oacc[db], 0,0,0);
      }
    }
  }
  float lsr[4];
  #pragma unroll
  for(int r=0;r<4;r++) lsr[r] = 1.0f / __shfl(l_run, (lg<<2)+r);
  #pragma unroll
  for(int db=0;db<8;db++){
    #pragma unroll
    for(int r=0;r<4;r++){
      int row = q0w + (lg<<2) + r;
      O[((size_t)((b*SEQL + row)*NH) + h)*HD + (db<<4) + lr] = f2bf(oacc[db][r]*lsr[r]);
    }
  }
}

// ---------------- host launcher (exact r10 configuration, measured 849us) -------------
extern "C" void kernel_launch(void* const* d_in, const int* in_sizes, int n_in,
                              void* d_out, int out_size, void* d_ws, size_t ws_size,
                              hipStream_t stream){
  const float* x   = (const float*)d_in[0];
  const float* anw = (const float*)d_in[1];
  const float* qw  = (const float*)d_in[2];
  const float* kw  = (const float*)d_in[3];
  const float* vw  = (const float*)d_in[4];
  const float* ow  = (const float*)d_in[5];
  const float* fnw = (const float*)d_in[6];
  const float* gw  = (const float*)d_in[7];
  const float* uw  = (const float*)d_in[8];
  const float* dw  = (const float*)d_in[9];
  float* out = (float*)d_out;

  char* ws = (char*)d_ws;
  size_t off = 0;
  auto alloc = [&](size_t bytes)->char*{ char* p = ws + off; off += (bytes + 255) & ~(size_t)255; return p; };
  unsigned short* Wbuf = (unsigned short*)alloc((size_t)INTERD*HID*2);     // 32 MB
  unsigned short* hb   = (unsigned short*)alloc((size_t)NTOK*HID*2);       // 16 MB
  unsigned short* qkvb = (unsigned short*)alloc((size_t)NTOK*3*HID*2);     // 48 MB
  unsigned short* aob  = (unsigned short*)alloc((size_t)NTOK*HID*2);       // 16 MB
  float*          x1   = (float*)alloc((size_t)NTOK*HID*4);                // 32 MB
  float*          cosb = (float*)alloc((size_t)SEQL*64*4);
  float*          sinb = (float*)alloc((size_t)SEQL*64*4);
  unsigned short* gb   = qkvb;                // 64 MB overlay (qkvb+aob), dead after O-proj
  unsigned short* VT   = (unsigned short*)x1; // 16 MB overlay: x1 written only after attn
  if(ws_size < off){ k_sentinel<<<1,1,0,stream>>>(out); return; }

  k_ropetab<<<SEQL, 64, 0, stream>>>(cosb, sinb);

  // ---- attention sublayer ----
  k_rmsnorm<<<NTOK, 256, 0, stream>>>(x, anw, hb);
  k_cvt<<<HID*HID/1024, 256, 0, stream>>>(qw, Wbuf,             HID*HID/4);
  k_cvt<<<HID*HID/1024, 256, 0, stream>>>(kw, Wbuf +   HID*HID, HID*HID/4);
  k_cvt<<<HID*HID/1024, 256, 0, stream>>>(vw, Wbuf + 2*HID*HID, HID*HID/4);
  k_gemmN<0><<<16*(3*HID/128), 512, 0, stream>>>(hb, Wbuf, qkvb, nullptr, nullptr, NTOK, 3*HID, HID);  // 768
  k_rope<<<(NTOK*NH*64)/256, 256, 0, stream>>>(qkvb,        3*HID, cosb, sinb, 0.08838834764831845f);
  k_rope<<<(NTOK*NH*64)/256, 256, 0, stream>>>(qkvb +  HID, 3*HID, cosb, sinb, 1.0f);
  k_transpose_v<<<NBATCH*NH*(SEQL/64), 256, 0, stream>>>(qkvb + 2*HID, 3*HID, VT);
  k_attn<<<(SEQL/64)*NBATCH*NH, 256, 0, stream>>>(qkvb, qkvb + HID, 3*HID, VT, aob);
  k_cvt<<<HID*HID/1024, 256, 0, stream>>>(ow, Wbuf, HID*HID/4);
  k_gemmN<1><<<16*(HID/128), 512, 0, stream>>>(aob, Wbuf, x1, x, nullptr, NTOK, HID, HID);             // 256

  // ---- MLP sublayer ----
  k_rmsnorm<<<NTOK, 256, 0, stream>>>(x1, fnw, hb);
  k_cvt<<<INTERD*HID/1024, 256, 0, stream>>>(gw, Wbuf, INTERD*HID/4);
  k_gemm8<0><<<(NTOK/256)*(INTERD/256), 512, 0, stream>>>(hb, Wbuf, gb, nullptr, nullptr, NTOK, INTERD, HID); // 512
  k_cvt<<<INTERD*HID/1024, 256, 0, stream>>>(uw, Wbuf, INTERD*HID/4);
  k_gemm8<2><<<(NTOK/256)*(INTERD/256), 512, 0, stream>>>(hb, Wbuf, gb, nullptr, gb, NTOK, INTERD, HID);      // 512
  k_cvt<<<INTERD*HID/1024, 256, 0, stream>>>(dw, Wbuf, INTERD*HID/4);
  k_gemmN<1><<<16*(HID/128), 512, 0, stream>>>(gb, Wbuf, out, x1, nullptr, NTOK, HID, INTERD);         // 256
}

// Round 17
// 844.208 us; speedup vs baseline: 1.1994x; 1.0100x over previous
//
#include <hip/hip_runtime.h>
#include <math.h>

#define HID 2048
#define NH 16
#define HD 128
#define INTERD 8192
#define SEQL 2048
#define NBATCH 2
#define NTOK (NBATCH*SEQL)

typedef float f32x4 __attribute__((ext_vector_type(4)));
typedef __bf16 bfx8 __attribute__((ext_vector_type(8)));

__device__ __forceinline__ float bf2f(unsigned short u){
  union { float f; unsigned v; } c; c.v = ((unsigned)u)<<16; return c.f;
}
__device__ __forceinline__ unsigned short f2bf(float f){
  union { float f; unsigned v; } c; c.f = f;
  unsigned r = c.v + 0x7FFFu + ((c.v>>16)&1u);   // RNE
  return (unsigned short)(r>>16);
}

// async global->LDS, 16B/lane; LDS dest = wave-uniform base + lane*16 (proven r3-r16).
__device__ __forceinline__ void gll16(const unsigned short* g, void* l){
  __builtin_amdgcn_global_load_lds(
      (const __attribute__((address_space(1))) unsigned int*)(size_t)(const void*)g,
      (__attribute__((address_space(3))) unsigned int*)(unsigned int)(size_t)l,
      16, 0, 0);
}

__global__ void k_sentinel(float* out){ out[0] = 1.0e9f; }

// ---------------- fp32 -> bf16 conversion (single weight) ----------------
__global__ __launch_bounds__(256) void k_cvt(const float* __restrict__ in,
                                             unsigned short* __restrict__ out, int n4){
  int i = blockIdx.x*256 + threadIdx.x;
  if(i >= n4) return;
  float4 v = reinterpret_cast<const float4*>(in)[i];
  ushort4 o;
  o.x = f2bf(v.x); o.y = f2bf(v.y); o.z = f2bf(v.z); o.w = f2bf(v.w);
  reinterpret_cast<ushort4*>(out)[i] = o;
}

// ---------------- fp32 -> bf16: q,k,v,o weights in one launch (proven r13) -----------
__global__ __launch_bounds__(256) void k_cvt4(const float* __restrict__ s0,
                                              const float* __restrict__ s1,
                                              const float* __restrict__ s2,
                                              const float* __restrict__ s3,
                                              unsigned short* __restrict__ dst){
  int bid = blockIdx.x;                 // 4 * 4096 blocks
  int seg = bid >> 12, sub = bid & 4095;
  const float* src = seg==0 ? s0 : seg==1 ? s1 : seg==2 ? s2 : s3;
  int i = sub*256 + threadIdx.x;        // float4 units; HID*HID/4 = 4096*256 exactly
  float4 v = reinterpret_cast<const float4*>(src)[i];
  ushort4 o;
  o.x = f2bf(v.x); o.y = f2bf(v.y); o.z = f2bf(v.z); o.w = f2bf(v.w);
  reinterpret_cast<ushort4*>(dst + (size_t)seg*HID*HID)[i] = o;
}

// ---------------- RMSNorm (fp32 in) -> bf16 out ----------------
__global__ __launch_bounds__(256) void k_rmsnorm(const float* __restrict__ x,
                                                 const float* __restrict__ w,
                                                 unsigned short* __restrict__ out){
  int row = blockIdx.x, t = threadIdx.x;
  const float4* xr = reinterpret_cast<const float4*>(x + (size_t)row*HID);
  float4 a = xr[2*t], b = xr[2*t+1];
  float ss = a.x*a.x+a.y*a.y+a.z*a.z+a.w*a.w + b.x*b.x+b.y*b.y+b.z*b.z+b.w*b.w;
  #pragma unroll
  for(int o=1;o<64;o<<=1) ss += __shfl_xor(ss, o);
  __shared__ float red[4];
  if((t&63)==0) red[t>>6] = ss;
  __syncthreads();
  float sc = rsqrtf((red[0]+red[1]+red[2]+red[3])*(1.0f/HID) + 1e-6f);
  const float4* wr = reinterpret_cast<const float4*>(w);
  float4 wa = wr[2*t], wb = wr[2*t+1];
  ushort4 o1, o2;
  o1.x=f2bf(a.x*sc*wa.x); o1.y=f2bf(a.y*sc*wa.y); o1.z=f2bf(a.z*sc*wa.z); o1.w=f2bf(a.w*sc*wa.w);
  o2.x=f2bf(b.x*sc*wb.x); o2.y=f2bf(b.y*sc*wb.y); o2.z=f2bf(b.z*sc*wb.z); o2.w=f2bf(b.w*sc*wb.w);
  ushort4* orow = reinterpret_cast<ushort4*>(out + (size_t)row*HID);
  orow[2*t] = o1; orow[2*t+1] = o2;
}

// ---------------- RoPE tables ----------------
__global__ void k_ropetab(float* __restrict__ cs, float* __restrict__ sn){
  int s = blockIdx.x, j = threadIdx.x;   // 64 threads
  float invf = powf(10000.0f, -(float)j*(1.0f/64.0f));
  float ang = (float)s * invf;
  float c, si;
  sincosf(ang, &si, &c);
  cs[s*64+j] = c; sn[s*64+j] = si;
}

// ---------------- RoPE for Q AND K in one launch (proven r13) --------------------------
__global__ __launch_bounds__(256) void k_rope2(unsigned short* qk, int ld,
                                               const float* __restrict__ cs,
                                               const float* __restrict__ sn, float qscale){
  int gid = blockIdx.x*256 + threadIdx.x;
  const int half = NTOK*NH*64;
  int sel = gid >= half;                 // 0 = Q (scaled), 1 = K
  int g = sel ? gid - half : gid;
  int j = g & 63;
  int rh = g >> 6;                       // tok*NH + h
  int tok = rh >> 4, h = rh & 15;
  int s = tok & (SEQL-1);
  unsigned short* base = qk + (size_t)tok*ld + sel*HID + h*HD;
  float scale = sel ? 1.0f : qscale;
  float c = cs[s*64+j], sv = sn[s*64+j];
  float x1 = bf2f(base[j]), x2 = bf2f(base[j+64]);
  base[j]    = f2bf((x1*c - x2*sv)*scale);
  base[j+64] = f2bf((x2*c + x1*sv)*scale);
}

// ---------------- V transpose: VT[b,h,d,s] <- V[tok][ld] (bf16) ----------------
__global__ __launch_bounds__(256) void k_transpose_v(const unsigned short* __restrict__ V,
                                                     int ld,
                                                     unsigned short* __restrict__ VT){
  __shared__ unsigned short T[64*136];
  int bid = blockIdx.x;
  int sb = bid & 31, h = (bid>>5) & 15, b = bid>>9;
  int t = threadIdx.x;
  int s0 = sb<<6;
  int sl = t>>2, dc = (t&3)<<5;
  const unsigned short* src = V + (size_t)(b*SEQL + s0 + sl)*ld + h*HD + dc;
  #pragma unroll
  for(int p=0;p<4;p++){
    bfx8 v = *reinterpret_cast<const bfx8*>(src + p*8);
    *reinterpret_cast<bfx8*>(&T[sl*136 + dc + p*8]) = v;
  }
  __syncthreads();
  int d = t>>1, sh = (t&1)<<5;
  unsigned short* dst = VT + ((size_t)((b*NH + h)*HD + d))*SEQL + s0 + sh;
  #pragma unroll
  for(int p=0;p<4;p++){
    union { bfx8 v; unsigned short u[8]; } o;
    #pragma unroll
    for(int j=0;j<8;j++) o.u[j] = T[(sh + p*8 + j)*136 + d];
    *reinterpret_cast<bfx8*>(dst + p*8) = o.v;
  }
}

// ---- shared pipeline helpers ----
#define BAR   __builtin_amdgcn_s_barrier()
#define LGKM0 { asm volatile("s_waitcnt lgkmcnt(0)":::"memory"); __builtin_amdgcn_sched_barrier(0); }
#define PRIO1 __builtin_amdgcn_s_setprio(1)
#define PRIO0 __builtin_amdgcn_s_setprio(0)

// ==================== GEMM 8-phase (r9, proven 190us on INTERD): gate / up ============
// BM=BN=256, BK=64; 512 thr = 8 waves (2M x 4N); wave-tile 128x64 (acc 8x4).
// 2 LDS slots (even/odd K-tile). Counted vmcnt at ph3 (4) and ph7 (8), never 0.
template<int EPI>
__global__ __launch_bounds__(512, 2) void k_gemm8(const unsigned short* __restrict__ A,
                                                  const unsigned short* __restrict__ W,
                                                  void* out, const float* __restrict__ resid,
                                                  const unsigned short* gbuf,
                                                  int M, int N, int K){
  __shared__ __align__(16) char lds[2][65536];   // slot: A[256][64]@0, B[256][64]@32768
  int xcd = blockIdx.x & 7, idx = blockIdx.x >> 3;
  int bm0 = (idx & 15) << 8;
  int bn0 = ((idx >> 4) + xcd*(N >> 11)) << 8;
  int t = threadIdx.x, w = t>>6, l = t&63, lr = l&15, lg = l>>4;
  int wm = w>>2, wn = w&3;
  int lrow = l>>3, lcs = (l&7) ^ lrow;
  int nt = K >> 7;

  f32x4 z = {0.f,0.f,0.f,0.f};
  f32x4 acc[8][4];
  #pragma unroll
  for(int i=0;i<8;i++){ acc[i][0]=z; acc[i][1]=z; acc[i][2]=z; acc[i][3]=z; }

  const unsigned short* sa[2][2];
  const unsigned short* sb[2][2];
  #pragma unroll
  for(int h=0;h<2;h++)
    #pragma unroll
    for(int p=0;p<2;p++){
      int r = h*128 + p*64 + (w<<3) + lrow;
      sa[h][p] = A + (size_t)(bm0 + r)*K + lcs*8;
      sb[h][p] = W + (size_t)(bn0 + r)*K + lcs*8;
    }

  #define STG_A(s, h, kk) { \
    _Pragma("unroll") for(int p=0;p<2;p++){ \
      int rb = ((h)*128 + p*64 + (w<<3))*128; \
      gll16(sa[h][p] + (kk), lds[s] + rb); } }
  #define STG_B(s, h, kk) { \
    _Pragma("unroll") for(int p=0;p<2;p++){ \
      int rb = ((h)*128 + p*64 + (w<<3))*128; \
      gll16(sb[h][p] + (kk), lds[s] + 32768 + rb); } }
  #define LD_AF(dst, s, fm0) { \
    _Pragma("unroll") for(int i=0;i<4;i++){ \
      int row = wm*128 + ((fm0)+i)*16 + lr; \
      _Pragma("unroll") for(int ks=0;ks<2;ks++) \
        dst[i][ks] = *reinterpret_cast<const bfx8*>(lds[s] + row*128 + ((((ks<<2)+lg)^(row&7))<<4)); } }
  #define LD_BF(dst, s, fn0) { \
    _Pragma("unroll") for(int i=0;i<2;i++){ \
      int row = wn*64 + ((fn0)+i)*16 + lr; \
      _Pragma("unroll") for(int ks=0;ks<2;ks++) \
        dst[i][ks] = *reinterpret_cast<const bfx8*>(lds[s] + 32768 + row*128 + ((((ks<<2)+lg)^(row&7))<<4)); } }
  #define MM(qm, qn, AF, BF) { \
    _Pragma("unroll") for(int i=0;i<4;i++) \
    _Pragma("unroll") for(int j=0;j<2;j++) \
    _Pragma("unroll") for(int ks=0;ks<2;ks++) \
      acc[(qm)*4+i][(qn)*2+j] = __builtin_amdgcn_mfma_f32_16x16x32_bf16(AF[i][ks], BF[j][ks], acc[(qm)*4+i][(qn)*2+j], 0,0,0); }

  STG_A(0,0,0)  STG_B(0,0,0)  STG_A(0,1,0)  STG_B(0,1,0)
  STG_A(1,0,64) STG_B(1,0,64) STG_A(1,1,64) STG_B(1,1,64)
  asm volatile("s_waitcnt vmcnt(8)":::"memory");
  BAR;

  bfx8 afl[4][2], afh[4][2], bfl[2][2], bfh[2][2];

  for(int it=0; it<nt; ++it){
    int k2 = (2*it+2 < 2*nt) ? ((2*it+2)<<6) : 0;
    int k3 = (2*it+3 < 2*nt) ? ((2*it+3)<<6) : 64;
    LD_AF(afl,0,0) LD_BF(bfl,0,0)
    asm volatile("s_waitcnt lgkmcnt(8)":::"memory");
    BAR; LGKM0 PRIO1; MM(0,0,afl,bfl) PRIO0; BAR;
    LD_BF(bfh,0,2)
    BAR; LGKM0 PRIO1; MM(0,1,afl,bfh) PRIO0; BAR;
    LD_AF(afh,0,4)
    BAR; LGKM0 PRIO1; MM(1,0,afh,bfl) PRIO0; BAR;
    STG_A(0,0,k2) STG_B(0,0,k2)
    BAR; PRIO1; MM(1,1,afh,bfh) PRIO0;
    asm volatile("s_waitcnt vmcnt(4)":::"memory");
    BAR;
    LD_AF(afl,1,0) LD_BF(bfl,1,0)
    STG_A(0,1,k2) STG_B(0,1,k2)
    asm volatile("s_waitcnt lgkmcnt(8)":::"memory");
    BAR; LGKM0 PRIO1; MM(0,0,afl,bfl) PRIO0; BAR;
    LD_BF(bfh,1,2)
    BAR; LGKM0 PRIO1; MM(0,1,afl,bfh) PRIO0; BAR;
    LD_AF(afh,1,4)
    STG_B(1,0,k3) STG_B(1,1,k3)
    BAR; LGKM0 PRIO1; MM(1,0,afh,bfl) PRIO0; BAR;
    STG_A(1,0,k3) STG_A(1,1,k3)
    BAR; PRIO1; MM(1,1,afh,bfh) PRIO0;
    asm volatile("s_waitcnt vmcnt(8)":::"memory");
    BAR;
  }
  #undef STG_A
  #undef STG_B
  #undef LD_AF
  #undef LD_BF
  #undef MM

  #pragma unroll
  for(int fm=0;fm<8;fm++){
    #pragma unroll
    for(int rr=0;rr<4;rr++){
      int row = bm0 + wm*128 + fm*16 + (lg<<2) + rr;
      #pragma unroll
      for(int fn=0;fn<4;fn++){
        int col = bn0 + wn*64 + fn*16 + lr;
        size_t o = (size_t)row*N + col;
        float v = acc[fm][fn][rr];
        if(EPI==0){
          reinterpret_cast<unsigned short*>(out)[o] = f2bf(v);
        } else if(EPI==1){
          reinterpret_cast<float*>(out)[o] = resid[o] + v;
        } else {
          float g = bf2f(gbuf[o]);
          float sg = g / (1.0f + __expf(-g));
          reinterpret_cast<unsigned short*>(out)[o] = f2bf(sg*v);
        }
      }
    }
  }
}

// ==================== GEMM-N (r10, proven): 256x128 tile, 3-slot — QKV / O / down =====
template<int EPI>
__global__ __launch_bounds__(512, 2) void k_gemmN(const unsigned short* __restrict__ A,
                                                  const unsigned short* __restrict__ W,
                                                  void* out, const float* __restrict__ resid,
                                                  const unsigned short* gbuf,
                                                  int M, int N, int K){
  __shared__ __align__(16) char lds[3*49152];
  int xcd = blockIdx.x & 7, idx = blockIdx.x >> 3;
  int bm0 = ((xcd<<1) + (idx&1)) << 8;      // 16 m-tiles, 2 per XCD
  int bn0 = (idx>>1) << 7;                  // N/128 n-tiles
  int t = threadIdx.x, w = t>>6, l = t&63, lr = l&15, lg = l>>4;
  int wm = w>>1, wn = w&1;
  int lrow = l>>3, lcs = (l&7) ^ lrow;
  int nt = K >> 6;

  f32x4 z = {0.f,0.f,0.f,0.f};
  f32x4 acc[4][4];
  #pragma unroll
  for(int i=0;i<4;i++){ acc[i][0]=z; acc[i][1]=z; acc[i][2]=z; acc[i][3]=z; }

  const unsigned short* sa[4];
  const unsigned short* sb[2];
  #pragma unroll
  for(int p=0;p<4;p++) sa[p] = A + (size_t)(bm0 + p*64 + (w<<3) + lrow)*K + lcs*8;
  #pragma unroll
  for(int p=0;p<2;p++) sb[p] = W + (size_t)(bn0 + p*64 + (w<<3) + lrow)*K + lcs*8;

  #define NSTG_A(Lp, kk) { _Pragma("unroll") for(int p=0;p<4;p++) \
      gll16(sa[p] + (kk), (Lp) + (p*64 + (w<<3))*128); }
  #define NSTG_B(Lp, kk) { _Pragma("unroll") for(int p=0;p<2;p++) \
      gll16(sb[p] + (kk), (Lp) + 32768 + (p*64 + (w<<3))*128); }
  #define NLD(Lc, ks) { \
    _Pragma("unroll") for(int i=0;i<4;i++){ int row = (wm<<6) + i*16 + lr; \
      af[i] = *reinterpret_cast<const bfx8*>((Lc) + row*128 + ((((ks<<2)+lg)^(row&7))<<4)); } \
    _Pragma("unroll") for(int j=0;j<4;j++){ int row = (wn<<6) + j*16 + lr; \
      bq[j] = *reinterpret_cast<const bfx8*>((Lc) + 32768 + row*128 + ((((ks<<2)+lg)^(row&7))<<4)); } }
  #define NMM { _Pragma("unroll") for(int i=0;i<4;i++) \
                _Pragma("unroll") for(int j=0;j<4;j++) \
      acc[i][j] = __builtin_amdgcn_mfma_f32_16x16x32_bf16(af[i], bq[j], acc[i][j], 0,0,0); }

  char* S0 = lds; char* S1 = lds + 49152; char* S2 = lds + 98304;
  NSTG_A(S0, 0) NSTG_B(S0, 0) NSTG_A(S1, 64) NSTG_B(S1, 64)
  asm volatile("s_waitcnt vmcnt(6)":::"memory");
  BAR;

  bfx8 af[4], bq[4];
  for(int kt=0; kt<nt; ++kt){
    int k2 = (kt+2 < nt) ? ((kt+2)<<6) : 0;   // wrap: stale-but-safe tail staging
    NLD(S0, 0)
    NSTG_A(S2, k2)
    BAR; LGKM0 PRIO1; NMM PRIO0; BAR;
    NLD(S0, 1)
    NSTG_B(S2, k2)
    BAR; LGKM0 PRIO1; NMM PRIO0;
    asm volatile("s_waitcnt vmcnt(6)":::"memory");
    BAR;
    char* tmp = S0; S0 = S1; S1 = S2; S2 = tmp;
  }
  #undef NSTG_A
  #undef NSTG_B
  #undef NLD
  #undef NMM

  #pragma unroll
  for(int fm=0;fm<4;fm++){
    #pragma unroll
    for(int rr=0;rr<4;rr++){
      int row = bm0 + (wm<<6) + fm*16 + (lg<<2) + rr;
      #pragma unroll
      for(int fn=0;fn<4;fn++){
        int col = bn0 + (wn<<6) + fn*16 + lr;
        size_t o = (size_t)row*N + col;
        float v = acc[fm][fn][rr];
        if(EPI==0){
          reinterpret_cast<unsigned short*>(out)[o] = f2bf(v);
        } else if(EPI==1){
          reinterpret_cast<float*>(out)[o] = resid[o] + v;
        } else {
          float g = bf2f(gbuf[o]);
          float sg = g / (1.0f + __expf(-g));
          reinterpret_cast<unsigned short*>(out)[o] = f2bf(sg*v);
        }
      }
    }
  }
}

// ---------------- Flash attention, causal (unchanged from rounds 4-16) ----------------
__global__ __launch_bounds__(256) void k_attn(const unsigned short* __restrict__ Q,
                                              const unsigned short* __restrict__ Kb,
                                              int ldqk,
                                              const unsigned short* __restrict__ VT,
                                              unsigned short* __restrict__ O){
  __shared__ unsigned short Klds[64*128];
  __shared__ unsigned short Vlds[128*64];
  __shared__ unsigned short Plds[4][16*72];

  int bid = blockIdx.x;
  int xcd = bid & 7, idx = bid >> 3;
  int bh = xcd*4 + (idx & 3);
  int qt = 31 - (idx >> 2);
  int h = bh & 15, b = bh >> 4;
  int q0 = qt << 6;
  int t = threadIdx.x, w = t>>6, l = t&63, lr = l&15, lg = l>>4;
  int q0w = q0 + (w<<4);

  bfx8 qf[4];
  const unsigned short* qrow = Q + (size_t)(b*SEQL + q0w + lr)*ldqk + h*HD;
  #pragma unroll
  for(int ds=0;ds<4;ds++) qf[ds] = *reinterpret_cast<const bfx8*>(qrow + ds*32 + lg*8);

  f32x4 z = {0.f,0.f,0.f,0.f};
  f32x4 oacc[8];
  #pragma unroll
  for(int i=0;i<8;i++) oacc[i] = z;
  float m_run = -1e30f, l_run = 0.f;

  int srow = t>>3, sch = t&7;
  int ntile = qt + 1;
  for(int tl=0; tl<ntile; ++tl){
    int k0 = tl << 6;
    __syncthreads();
    #pragma unroll
    for(int pr=0;pr<2;pr++){
      int row = srow + (pr<<5);
      const unsigned short* ks = Kb + (size_t)(b*SEQL + k0 + row)*ldqk + h*HD;
      #pragma unroll
      for(int pc=0;pc<2;pc++){
        int cl = sch + (pc<<3);
        *reinterpret_cast<bfx8*>((char*)Klds + row*256 + ((cl ^ (row&7))<<4)) =
            *reinterpret_cast<const bfx8*>(ks + cl*8);
      }
    }
    #pragma unroll
    for(int pr=0;pr<4;pr++){
      int row = srow + (pr<<5);
      const unsigned short* vs = VT + ((size_t)((b*NH + h)*HD + row))*SEQL + k0;
      *reinterpret_cast<bfx8*>((char*)Vlds + row*128 + ((sch ^ (row&7))<<4)) =
          *reinterpret_cast<const bfx8*>(vs + sch*8);
    }
    __syncthreads();

    f32x4 sAcc[4];
    sAcc[0]=z; sAcc[1]=z; sAcc[2]=z; sAcc[3]=z;
    #pragma unroll
    for(int ds=0;ds<4;ds++){
      int cha = (ds<<2) + lg;
      #pragma unroll
      for(int kg=0;kg<4;kg++){
        int row = (kg<<4) + lr;
        bfx8 ka = *reinterpret_cast<const bfx8*>((char*)Klds + row*256 + ((cha ^ (row&7))<<4));
        sAcc[kg] = __builtin_amdgcn_mfma_f32_16x16x32_bf16(ka, qf[ds], sAcc[kg], 0,0,0);
      }
    }
    int qg = q0w + lr;
    float p[16];
    float mx = -1e30f;
    #pragma unroll
    for(int kg=0;kg<4;kg++){
      #pragma unroll
      for(int r=0;r<4;r++){
        int kk = k0 + (kg<<4) + (lg<<2) + r;
        float v = (kk <= qg) ? sAcc[kg][r] : -1e30f;
        p[kg*4+r] = v; mx = fmaxf(mx, v);
      }
    }
    mx = fmaxf(mx, __shfl_xor(mx,16));
    mx = fmaxf(mx, __shfl_xor(mx,32));
    float m_new = fmaxf(m_run, mx);
    float fac = __expf(m_run - m_new);
    float ts = 0.f;
    #pragma unroll
    for(int i=0;i<16;i++){ p[i] = __expf(p[i]-m_new); ts += p[i]; }
    ts += __shfl_xor(ts,16); ts += __shfl_xor(ts,32);
    l_run = l_run*fac + ts;
    m_run = m_new;
    char* pb = (char*)&Plds[w][0] + lr*144 + lg*8;
    #pragma unroll
    for(int kg=0;kg<4;kg++){
      unsigned pa = (unsigned)f2bf(p[kg*4+0]) | ((unsigned)f2bf(p[kg*4+1])<<16);
      unsigned pc = (unsigned)f2bf(p[kg*4+2]) | ((unsigned)f2bf(p[kg*4+3])<<16);
      *reinterpret_cast<uint2*>(pb + kg*32) = make_uint2(pa, pc);
    }
    float facr[4];
    #pragma unroll
    for(int r=0;r<4;r++) facr[r] = __shfl(fac, (lg<<2)+r);
    #pragma unroll
    for(int db=0;db<8;db++){
      f32x4 o = oacc[db];
      o[0]*=facr[0]; o[1]*=facr[1]; o[2]*=facr[2]; o[3]*=facr[3];
      oacc[db] = o;
    }
    __syncthreads();
    #pragma unroll
    for(int kh=0;kh<2;kh++){
      bfx8 pf = *reinterpret_cast<const bfx8*>((char*)&Plds[w][0] + lr*144 + kh*64 + lg*16);
      #pragma unroll
      for(int db=0;db<8;db++){
        int row = (db<<4) + lr;
        int lc = (kh<<2) + lg;
        bfx8 vf = *reinterpret_cast<const bfx8*>((char*)Vlds + row*128 + ((lc ^ (row&7))<<4));
        oacc[db] = __builtin_amdgcn_mfma_f32_16x16x32_bf16(pf, vf, oacc[db], 0,0,0);
      }
    }
  }
  float lsr[4];
  #pragma unroll
  for(int r=0;r<4;r++) lsr[r] = 1.0f / __shfl(l_run, (lg<<2)+r);
  #pragma unroll
  for(int db=0;db<8;db++){
    #pragma unroll
    for(int r=0;r<4;r++){
      int row = q0w + (lg<<2) + r;
      O[((size_t)((b*SEQL + row)*NH) + h)*HD + (db<<4) + lr] = f2bf(oacc[db][r]*lsr[r]);
    }
  }
}

// ---------------- host launcher (r10 config + r13-proven cvt4/rope2 fusions) ----------
extern "C" void kernel_launch(void* const* d_in, const int* in_sizes, int n_in,
                              void* d_out, int out_size, void* d_ws, size_t ws_size,
                              hipStream_t stream){
  const float* x   = (const float*)d_in[0];
  const float* anw = (const float*)d_in[1];
  const float* qw  = (const float*)d_in[2];
  const float* kw  = (const float*)d_in[3];
  const float* vw  = (const float*)d_in[4];
  const float* ow  = (const float*)d_in[5];
  const float* fnw = (const float*)d_in[6];
  const float* gw  = (const float*)d_in[7];
  const float* uw  = (const float*)d_in[8];
  const float* dw  = (const float*)d_in[9];
  float* out = (float*)d_out;

  char* ws = (char*)d_ws;
  size_t off = 0;
  auto alloc = [&](size_t bytes)->char*{ char* p = ws + off; off += (bytes + 255) & ~(size_t)255; return p; };
  unsigned short* Wbuf = (unsigned short*)alloc((size_t)INTERD*HID*2);     // 32 MB (q|k|v|o, then g, u, d)
  unsigned short* hb   = (unsigned short*)alloc((size_t)NTOK*HID*2);       // 16 MB
  unsigned short* qkvb = (unsigned short*)alloc((size_t)NTOK*3*HID*2);     // 48 MB
  unsigned short* aob  = (unsigned short*)alloc((size_t)NTOK*HID*2);       // 16 MB
  float*          x1   = (float*)alloc((size_t)NTOK*HID*4);                // 32 MB
  float*          cosb = (float*)alloc((size_t)SEQL*64*4);
  float*          sinb = (float*)alloc((size_t)SEQL*64*4);
  unsigned short* gb   = qkvb;                // 64 MB overlay (qkvb+aob), dead after O-proj
  unsigned short* VT   = (unsigned short*)x1; // 16 MB overlay: x1 written only after attn
  if(ws_size < off){ k_sentinel<<<1,1,0,stream>>>(out); return; }

  k_ropetab<<<SEQL, 64, 0, stream>>>(cosb, sinb);

  // ---- attention sublayer ----
  k_rmsnorm<<<NTOK, 256, 0, stream>>>(x, anw, hb);
  k_cvt4<<<4*(HID*HID/1024), 256, 0, stream>>>(qw, kw, vw, ow, Wbuf);   // q|k|v|o -> Wbuf
  k_gemmN<0><<<16*(3*HID/128), 512, 0, stream>>>(hb, Wbuf, qkvb, nullptr, nullptr, NTOK, 3*HID, HID);  // 768
  k_rope2<<<2*(NTOK*NH*64)/256, 256, 0, stream>>>(qkvb, 3*HID, cosb, sinb, 0.08838834764831845f);
  k_transpose_v<<<NBATCH*NH*(SEQL/64), 256, 0, stream>>>(qkvb + 2*HID, 3*HID, VT);
  k_attn<<<(SEQL/64)*NBATCH*NH, 256, 0, stream>>>(qkvb, qkvb + HID, 3*HID, VT, aob);
  k_gemmN<1><<<16*(HID/128), 512, 0, stream>>>(aob, Wbuf + 3*HID*HID, x1, x, nullptr, NTOK, HID, HID); // 256

  // ---- MLP sublayer ----
  k_rmsnorm<<<NTOK, 256, 0, stream>>>(x1, fnw, hb);
  k_cvt<<<INTERD*HID/1024, 256, 0, stream>>>(gw, Wbuf, INTERD*HID/4);
  k_gemm8<0><<<(NTOK/256)*(INTERD/256), 512, 0, stream>>>(hb, Wbuf, gb, nullptr, nullptr, NTOK, INTERD, HID); // 512
  k_cvt<<<INTERD*HID/1024, 256, 0, stream>>>(uw, Wbuf, INTERD*HID/4);
  k_gemm8<2><<<(NTOK/256)*(INTERD/256), 512, 0, stream>>>(hb, Wbuf, gb, nullptr, gb, NTOK, INTERD, HID);      // 512
  k_cvt<<<INTERD*HID/1024, 256, 0, stream>>>(dw, Wbuf, INTERD*HID/4);
  k_gemmN<1><<<16*(HID/128), 512, 0, stream>>>(gb, Wbuf, out, x1, nullptr, NTOK, HID, INTERD);         // 256
}